// Round 10
// baseline (414.892 us; speedup 1.0000x reference)
//
#include <hip/hip_runtime.h>
#include <math.h>

// ---------------------------------------------------------------------------
// Problem constants: B=16, DIM=256, H=W=64, HEADS=8, C2=16, CF=9, DC=64
// Activations for MFMA are TOKEN-major bf16 [b][4096][C] (K-contiguous).
// f32 kept only for: x (input), qkv (attention), final out.
// ---------------------------------------------------------------------------

typedef __attribute__((ext_vector_type(8))) short bf16x8;
typedef __attribute__((ext_vector_type(4))) float f32x4;

__device__ __forceinline__ float gelu_f(float v) {
    return 0.5f * v * (1.0f + erff(v * 0.70710678118654752440f));
}
__device__ __forceinline__ unsigned short f2bf(float f) {
    unsigned u = __builtin_bit_cast(unsigned, f);
    u += 0x7fffu + ((u >> 16) & 1u);
    return (unsigned short)(u >> 16);
}
__device__ __forceinline__ float bf2f(unsigned short h) {
    return __builtin_bit_cast(float, (unsigned)h << 16);
}
__device__ __forceinline__ void store8bf(unsigned short* p, const float* v) {
    unsigned short h[8];
#pragma unroll
    for (int i = 0; i < 8; i++) h[i] = f2bf(v[i]);
    uint4 o;
    o.x = h[0] | ((unsigned)h[1] << 16);
    o.y = h[2] | ((unsigned)h[3] << 16);
    o.z = h[4] | ((unsigned)h[5] << 16);
    o.w = h[6] | ((unsigned)h[7] << 16);
    *(uint4*)p = o;
}

// global -> LDS direct 16B async copy (wave-uniform LDS base, lane scatter i*16)
typedef __attribute__((address_space(1))) void gvoid;
typedef __attribute__((address_space(3))) void svoid;
__device__ __forceinline__ void gl_lds16(const unsigned short* g, unsigned short* l) {
    __builtin_amdgcn_global_load_lds((gvoid*)g, (svoid*)l, 16, 0, 0);
}

// ---------------------------------------------------------------------------
// Merged f32 -> bf16 weight converts (6 segments, one launch)
// ---------------------------------------------------------------------------
__global__ __launch_bounds__(256) void cvt_all(
    const float* __restrict__ a0, unsigned short* __restrict__ d0, int m0,
    const float* __restrict__ a1, unsigned short* __restrict__ d1, int m1,
    const float* __restrict__ a2, unsigned short* __restrict__ d2, int m2,
    const float* __restrict__ a3, unsigned short* __restrict__ d3, int m3,
    const float* __restrict__ a4, unsigned short* __restrict__ d4, int m4,
    const float* __restrict__ a5, unsigned short* __restrict__ d5, int m5)
{
    int sy = blockIdx.y;
    int i = blockIdx.x * 256 + threadIdx.x;
    const float* s; unsigned short* d; int n;
    if      (sy == 0) { s = a0; d = d0; n = m0; }
    else if (sy == 1) { s = a1; d = d1; n = m1; }
    else if (sy == 2) { s = a2; d = d2; n = m2; }
    else if (sy == 3) { s = a3; d = d3; n = m3; }
    else if (sy == 4) { s = a4; d = d4; n = m4; }
    else              { s = a5; d = d5; n = m5; }
    if (i < n) d[i] = f2bf(s[i]);
}

// ---------------------------------------------------------------------------
// Merged conv-weight converts OIHW f32 -> bf16 [tap][oc][ic] (3 segments)
// ---------------------------------------------------------------------------
__global__ __launch_bounds__(256) void cvt_wconv_all(
    const float* __restrict__ w0, unsigned short* __restrict__ o0,
    const float* __restrict__ w1, unsigned short* __restrict__ o1,
    const float* __restrict__ w2, unsigned short* __restrict__ o2)
{
    int sy = blockIdx.y;
    const float* w; unsigned short* wb; int KK;
    if      (sy == 0) { w = w0; wb = o0; KK = 9;  }
    else if (sy == 1) { w = w1; wb = o1; KK = 25; }
    else              { w = w2; wb = o2; KK = 9;  }
    int idx = blockIdx.x * 256 + threadIdx.x;
    if (idx >= 64 * 64 * KK) return;
    int ic = idx & 63, oc = (idx >> 6) & 63, tap = idx >> 12;
    wb[tap * 4096 + oc * 64 + ic] = f2bf(w[(oc * 64 + ic) * KK + tap]);
}

// ---------------------------------------------------------------------------
// x [b][256][4096] f32 -> xT [b][4096][256] bf16 (LDS tile transpose)
// ---------------------------------------------------------------------------
__global__ __launch_bounds__(256) void cvt_xpose(
    const float* __restrict__ x, unsigned short* __restrict__ xT)
{
    __shared__ float tile[64][65];
    const int t = threadIdx.x;
    const int n0 = blockIdx.x * 64, c0 = blockIdx.y * 64, b = blockIdx.z;
    const float* xb = x + (long)b * 1048576;
#pragma unroll
    for (int i = 0; i < 16; i++) {
        int c = i * 4 + (t >> 6), n = t & 63;
        tile[c][n] = xb[(long)(c0 + c) * 4096 + n0 + n];
    }
    __syncthreads();
    unsigned short* xTb = xT + (long)b * 4096 * 256;
#pragma unroll
    for (int i = 0; i < 4; i++) {
        int n = i * 16 + (t >> 4), cc = (t & 15) * 4;
        unsigned short h0 = f2bf(tile[cc + 0][n]);
        unsigned short h1 = f2bf(tile[cc + 1][n]);
        unsigned short h2 = f2bf(tile[cc + 2][n]);
        unsigned short h3 = f2bf(tile[cc + 3][n]);
        uint2 val;
        val.x = h0 | ((unsigned)h1 << 16);
        val.y = h2 | ((unsigned)h3 << 16);
        *(uint2*)&xTb[(long)(n0 + n) * 256 + c0 + cc] = val;
    }
}

// ---------------------------------------------------------------------------
// MFMA bf16 GEMM v4: global_load_lds staging (round-8, FETCH fixed) +
// LDS-staged coalesced bf16 epilogue (fixes 1.87x WRITE inflation from 8-B
// scattered token-major stores). LDS addresses computed inline — no pointer
// arrays of __shared__ (gfx950 rejects the addrspacecast static init).
// ---------------------------------------------------------------------------
#define LDW 32

struct GSel {
    const unsigned short* in1;   // cols [0,c1) source (ld 64), may be null
    const unsigned short* W;     // weights, ld w_ld
    const float* bias;           // may be null
    int c1;
    int col_off;                 // outT column offset
};
struct GemmP {
    GSel sel0, sel1, sel2;
    const unsigned short* in2T;  // cols [c1,K) source (absolute col)
    long ld2;
    int w_ld, rowmap, otiles, K, mode, do_gelu;
    const unsigned short* addT;  // token-major bf16 residual (ld 256), may be null
    unsigned short* outT;        // token-major bf16 out
    int ldo;
    float* outF;                 // channel-major f32 out
    long bsF;
};

__global__ __launch_bounds__(256) void mfma_gemm(GemmP p)
{
    __shared__ unsigned short SM[16384];  // 32 KB: A at [buf*4096], B at [8192+buf*4096]
    const int t = threadIdx.x, b = blockIdx.z;
    const int n0 = blockIdx.x * 128;
    const unsigned sy = blockIdx.y;
    const int s  = sy / (unsigned)p.otiles;
    const int ot = sy % (unsigned)p.otiles;
    GSel g = p.sel0;
    if (s == 1) g = p.sel1;
    else if (s == 2) g = p.sel2;
    const int o0 = ot * 128;
    const int w = t >> 6, l = t & 63;
    const int fr = l & 15, fq = l >> 4;
    const int wr = (w >> 1) * 64, wc = (w & 1) * 64;
    const int lrow = l >> 2, lcol = (l & 3) * 8;

    // staging geometry: wave w owns LDS rows [32w,32w+16) and [32w+16,32w+32)
    const int ta0 = 32 * w + lrow, ta1 = ta0 + 16;
    int ra0 = o0 + ta0, ra1 = o0 + ta1;
    if (p.rowmap) {
        ra0 = ((ra0 >> 7) << 8) + (((ra0 >> 4) & 7) << 5) + 16 + (ra0 & 15);
        ra1 = ((ra1 >> 7) << 8) + (((ra1 >> 4) & 7) << 5) + 16 + (ra1 & 15);
    }
    const unsigned short* Ag0 = g.W + (long)ra0 * p.w_ld + lcol;
    const unsigned short* Ag1 = g.W + (long)ra1 * p.w_ld + lcol;
    const unsigned short* i1b = g.in1 ? g.in1 : p.in2T;
    const unsigned short* i1r0 = i1b + ((long)b * 4096 + n0 + ta0) * 64 + lcol;
    const unsigned short* i1r1 = i1r0 + 16L * 64;
    const unsigned short* i2r0 = p.in2T + ((long)b * 4096 + n0 + ta0) * p.ld2 + lcol;
    const unsigned short* i2r1 = i2r0 + 16L * p.ld2;

#define STAGE(BUF, KK) do {                                                    \
        gl_lds16(Ag0 + (KK), &SM[(BUF) * 4096 + (32 * w) * LDW]);              \
        gl_lds16(Ag1 + (KK), &SM[(BUF) * 4096 + (32 * w + 16) * LDW]);         \
        if ((KK) < g.c1) {                                                     \
            gl_lds16(i1r0 + (KK), &SM[8192 + (BUF) * 4096 + (32 * w) * LDW]);  \
            gl_lds16(i1r1 + (KK), &SM[8192 + (BUF) * 4096 + (32 * w + 16) * LDW]); \
        } else {                                                               \
            gl_lds16(i2r0 + (KK), &SM[8192 + (BUF) * 4096 + (32 * w) * LDW]);  \
            gl_lds16(i2r1 + (KK), &SM[8192 + (BUF) * 4096 + (32 * w + 16) * LDW]); \
        } } while (0)

    f32x4 acc[4][4];
#pragma unroll
    for (int m = 0; m < 4; m++)
#pragma unroll
        for (int n = 0; n < 4; n++) acc[m][n] = (f32x4){0.f, 0.f, 0.f, 0.f};

    STAGE(0, 0);
    __syncthreads();

    const int NK = p.K >> 5;
    for (int ks = 0; ks < NK; ks++) {
        const int cur = ks & 1;
        const int kn = (ks + 1) << 5;
        if (kn < p.K) STAGE(cur ^ 1, kn);      // async into other buffer
        bf16x8 af[4], bv[4];
#pragma unroll
        for (int m = 0; m < 4; m++)
            af[m] = *(const bf16x8*)&SM[cur * 4096 + (wr + m * 16 + fr) * LDW + fq * 8];
#pragma unroll
        for (int n = 0; n < 4; n++)
            bv[n] = *(const bf16x8*)&SM[8192 + cur * 4096 + (wc + n * 16 + fr) * LDW + fq * 8];
#pragma unroll
        for (int m = 0; m < 4; m++)
#pragma unroll
            for (int n = 0; n < 4; n++)
                acc[m][n] = __builtin_amdgcn_mfma_f32_16x16x32_bf16(af[m], bv[n], acc[m][n], 0, 0, 0);
        __syncthreads();                        // drains vmcnt (stage done) + lgkm
    }
#undef STAGE

    // ---- epilogue ----
    if (p.mode == 0) {
        // LDS-staged coalesced store: two passes of 64 tokens, tile [64][136]
        // (pad 136 shorts -> conflict-light on both phases). Each token row
        // goes out as contiguous 256 B via uint4 lanes.
#define EPW 136
#pragma unroll
        for (int pass = 0; pass < 2; pass++) {
            if ((w & 1) == pass) {               // waves whose wc == 64*pass
#pragma unroll
                for (int m = 0; m < 4; m++) {
                    int chm = wr + m * 16 + fq * 4;     // local channel 0..127
                    int ob = o0 + chm;
                    float bm[4] = {0.f, 0.f, 0.f, 0.f};
                    if (g.bias) {
#pragma unroll
                        for (int r = 0; r < 4; r++) bm[r] = g.bias[ob + r];
                    }
#pragma unroll
                    for (int n = 0; n < 4; n++) {
                        int tn = n * 16 + fr;            // local token 0..63
                        int ng = n0 + pass * 64 + tn;
                        float e[4];
#pragma unroll
                        for (int r = 0; r < 4; r++) {
                            e[r] = acc[m][n][r] + bm[r];
                            if (p.do_gelu) e[r] = gelu_f(e[r]);
                        }
                        if (p.addT) {
                            uint2 av = *(const uint2*)&p.addT[((long)b * 4096 + ng) * 256 + ob];
                            e[0] += bf2f((unsigned short)(av.x & 0xffff));
                            e[1] += bf2f((unsigned short)(av.x >> 16));
                            e[2] += bf2f((unsigned short)(av.y & 0xffff));
                            e[3] += bf2f((unsigned short)(av.y >> 16));
                        }
                        unsigned short h[4];
#pragma unroll
                        for (int r = 0; r < 4; r++) h[r] = f2bf(e[r]);
                        uint2 val;
                        val.x = h[0] | ((unsigned)h[1] << 16);
                        val.y = h[2] | ((unsigned)h[3] << 16);
                        *(uint2*)&SM[tn * EPW + chm] = val;
                    }
                }
            }
            __syncthreads();
            // readout: 1024 x 16B chunks; 16 chunks per token row (256 B)
#pragma unroll
            for (int i = 0; i < 4; i++) {
                int c = t + i * 256;
                int tn = c >> 4, pos = c & 15;
                uint4 v = *(const uint4*)&SM[tn * EPW + pos * 8];
                *(uint4*)&p.outT[((long)b * 4096 + n0 + pass * 64 + tn) * (long)p.ldo
                                 + g.col_off + o0 + pos * 8] = v;
            }
            __syncthreads();
        }
#undef EPW
    } else {
        // f32 channel-major epilogue (qkv / proj / out) — unchanged
#pragma unroll
        for (int m = 0; m < 4; m++) {
            int ob = o0 + wr + m * 16 + fq * 4;
            float bm[4] = {0.f, 0.f, 0.f, 0.f};
            if (g.bias) {
#pragma unroll
                for (int r = 0; r < 4; r++) bm[r] = g.bias[ob + r];
            }
#pragma unroll
            for (int n = 0; n < 4; n++) {
                int ng = n0 + wc + n * 16 + fr;
                float e[4];
#pragma unroll
                for (int r = 0; r < 4; r++) {
                    e[r] = acc[m][n][r] + bm[r];
                    if (p.do_gelu) e[r] = gelu_f(e[r]);
                }
#pragma unroll
                for (int r = 0; r < 4; r++)
                    p.outF[(long)b * p.bsF + (long)(ob + r) * 4096 + ng] = e[r];
            }
        }
    }
}

// ---------------------------------------------------------------------------
// MFMA conv (unchanged — passed).
// ---------------------------------------------------------------------------
template<int K>
__global__ __launch_bounds__(256) void conv_mfma(
    const unsigned short* __restrict__ inT, int ldin,
    const unsigned short* __restrict__ wb,
    unsigned short* __restrict__ outT)
{
    constexpr int R   = K / 2;
    constexpr int NR  = 2 + 2 * R;
    constexpr int W   = 64 + 2 * R;
    constexpr int ICP = 40;
    __shared__ unsigned short lds[NR * W * ICP];
    const int t = threadIdx.x;
    const int b = blockIdx.y;
    const int y0 = blockIdx.x * 2;
    const int w = t >> 6, l = t & 63;
    const int fr = l & 15, fq = l >> 4;
    const int ocw = (w & 1) * 32;
    const int rw  = w >> 1;

    f32x4 acc[2][4];
#pragma unroll
    for (int m = 0; m < 2; m++)
#pragma unroll
        for (int j = 0; j < 4; j++) acc[m][j] = (f32x4){0.f, 0.f, 0.f, 0.f};

    for (int kk = 0; kk < 64; kk += 32) {
        __syncthreads();
        for (int e = t; e < NR * W * 4; e += 256) {
            int part = e & 3;
            int px   = (e >> 2) % W;
            int row  = (e >> 2) / W;
            int gx = px - R, gy = y0 - R + row;
            uint4 v = {0u, 0u, 0u, 0u};
            if ((unsigned)gx < 64u && (unsigned)gy < 64u)
                v = *(const uint4*)&inT[((long)b * 4096 + gy * 64 + gx) * (long)ldin + kk + part * 8];
            *(uint4*)&lds[(row * W + px) * ICP + part * 8] = v;
        }
        __syncthreads();
#pragma unroll
        for (int ky = 0; ky < K; ky++) {
#pragma unroll
            for (int kx = 0; kx < K; kx++) {
                const unsigned short* wt = wb + ((long)((ky * K + kx) * 64 + ocw)) * 64 + kk;
                bf16x8 aw0 = *(const bf16x8*)&wt[fr * 64 + fq * 8];
                bf16x8 aw1 = *(const bf16x8*)&wt[(16 + fr) * 64 + fq * 8];
                const unsigned short* lp = &lds[((rw + ky) * W + kx) * ICP + fq * 8];
#pragma unroll
                for (int j = 0; j < 4; j++) {
                    bf16x8 bt = *(const bf16x8*)&lp[(j * 16 + fr) * ICP];
                    acc[0][j] = __builtin_amdgcn_mfma_f32_16x16x32_bf16(aw0, bt, acc[0][j], 0, 0, 0);
                    acc[1][j] = __builtin_amdgcn_mfma_f32_16x16x32_bf16(aw1, bt, acc[1][j], 0, 0, 0);
                }
            }
        }
    }
    const long tokbase = (long)b * 4096 + (y0 + rw) * 64;
#pragma unroll
    for (int mi = 0; mi < 2; mi++) {
        int oc0 = ocw + mi * 16 + fq * 4;
#pragma unroll
        for (int j = 0; j < 4; j++) {
            long tok = tokbase + j * 16 + fr;
            unsigned short h[4];
#pragma unroll
            for (int r = 0; r < 4; r++) h[r] = f2bf(acc[mi][j][r]);
            uint2 val;
            val.x = h[0] | ((unsigned)h[1] << 16);
            val.y = h[2] | ((unsigned)h[3] << 16);
            *(uint2*)&outT[tok * 64 + oc0] = val;
        }
    }
}

// ---------------------------------------------------------------------------
// Attention (f32, unchanged): reduce -> mats -> apply.
// ---------------------------------------------------------------------------
#define NC 128
#define ST 132

__global__ __launch_bounds__(256) void attn_reduce(
    const float* __restrict__ qkv, float* __restrict__ part)
{
    const int chunk = blockIdx.x, bh = blockIdx.y;
    const int b = bh >> 3, h = bh & 7;
    const int t = threadIdx.x;

    __shared__ float qch[16][ST], kch[16][ST];
    __shared__ float qfr[9][ST], qfi[9][ST], kfr[9][ST], kfi[9][ST];
    __shared__ float ct[9][16], st_[9][16];

    if (t < 144) {
        int f = t / 16, c = t % 16;
        float ang = 6.283185307179586f * (float)(f * c) / 16.0f;
        ct[f][c] = cosf(ang);
        st_[f][c] = sinf(ang);
    }

    const float* qbase = qkv + (long)b * 1572864 + (long)(16 * h) * 4096;
    const float* kbase = qbase + 128 * 4096;

    float s1 = 0.f, sfr = 0.f, sfi = 0.f;
    float qssp = 0.f, kssp = 0.f, qfssp = 0.f, kfssp = 0.f;
    const int c0 = t >> 4, d0 = t & 15;
    const int cf = t / 9, df = t % 9;
    const int rr = t >> 4, jj0 = t & 15;

    const int nlo = chunk * 512, nhi = nlo + 512;
    for (int n0 = nlo; n0 < nhi; n0 += NC) {
        __syncthreads();
#pragma unroll
        for (int i = 0; i < 8; i++) {
            int e = i * 256 + t, row = e >> 7, nn = e & 127;
            qch[row][nn] = qbase[(long)row * 4096 + n0 + nn];
            kch[row][nn] = kbase[(long)row * 4096 + n0 + nn];
        }
        __syncthreads();
        {
            int col = t & 127;
            bool isq = t < 128;
            float vv[16];
#pragma unroll
            for (int c = 0; c < 16; c++) vv[c] = isq ? qch[c][col] : kch[c][col];
#pragma unroll
            for (int f = 0; f < 9; f++) {
                float ar = 0.f, ai = 0.f;
#pragma unroll
                for (int c = 0; c < 16; c++) { ar += vv[c] * ct[f][c]; ai -= vv[c] * st_[f][c]; }
                if (isq) { qfr[f][col] = ar; qfi[f][col] = ai; }
                else     { kfr[f][col] = ar; kfi[f][col] = ai; }
            }
        }
#pragma unroll 4
        for (int n = 0; n < NC; n++) s1 += qch[c0][n] * kch[d0][n];
        for (int n = jj0; n < NC; n += 16) {
            float a = qch[rr][n]; qssp += a * a;
            float bq = kch[rr][n]; kssp += bq * bq;
        }
        __syncthreads();
        if (t < 81) {
#pragma unroll 4
            for (int n = 0; n < NC; n++) {
                float qr = qfr[cf][n], qi = qfi[cf][n];
                float kr = kfr[df][n], ki = kfi[df][n];
                sfr += qr * kr - qi * ki;
                sfi += qr * ki + qi * kr;
            }
        }
        if (t < 144) {
            int f = t >> 4;
            for (int n = jj0; n < NC; n += 16) {
                qfssp += qfr[f][n] * qfr[f][n] + qfi[f][n] * qfi[f][n];
                kfssp += kfr[f][n] * kfr[f][n] + kfi[f][n] * kfi[f][n];
            }
        }
    }

#pragma unroll
    for (int off = 8; off; off >>= 1) {
        qssp  += __shfl_xor(qssp, off);
        kssp  += __shfl_xor(kssp, off);
        qfssp += __shfl_xor(qfssp, off);
        kfssp += __shfl_xor(kfssp, off);
    }
    float* pb = part + (long)(bh * 8 + chunk) * 512;
    pb[t] = s1;
    if (t < 81) { pb[256 + t] = sfr; pb[337 + t] = sfi; }
    if (jj0 == 0) { pb[448 + rr] = qssp; pb[464 + rr] = kssp; }
    if (jj0 == 0 && t < 144) { pb[480 + rr] = qfssp; pb[489 + rr] = kfssp; }
}

__global__ __launch_bounds__(256) void attn_mats(
    const float* __restrict__ part,
    const float* __restrict__ temp1, const float* __restrict__ temp2,
    const float* __restrict__ tw1, const float* __restrict__ tw2,
    float* __restrict__ amats)
{
    const int bh = blockIdx.x;
    const int h = bh & 7;
    const int t = threadIdx.x;

    __shared__ float S1[256], Sfr[81], Sfi[81];
    __shared__ float qss[16], kss[16], qfss[9], kfss[9];

    float s1 = 0.f, sfr = 0.f, sfi = 0.f, a0 = 0.f, a1 = 0.f, a2 = 0.f, a3 = 0.f;
#pragma unroll
    for (int ch = 0; ch < 8; ch++) {
        const float* p = part + (long)(bh * 8 + ch) * 512;
        s1 += p[t];
        if (t < 81) { sfr += p[256 + t]; sfi += p[337 + t]; }
        if (t < 16) { a0 += p[448 + t]; a1 += p[464 + t]; }
        if (t < 9)  { a2 += p[480 + t]; a3 += p[489 + t]; }
    }
    S1[t] = s1;
    if (t < 81) { Sfr[t] = sfr; Sfi[t] = sfi; }
    if (t < 16) { qss[t] = a0; kss[t] = a1; }
    if (t < 9)  { qfss[t] = a2; kfss[t] = a3; }
    __syncthreads();

    const float t1s = temp1[h], t2s = temp2[h];
    float* am = amats + (long)bh * 448;
    if (t < 16) {
        int c = t;
        float nq = fmaxf(sqrtf(qss[c]), 1e-12f);
        float vals[16];
        float m = -1e30f;
#pragma unroll
        for (int d = 0; d < 16; d++) {
            float nk = fmaxf(sqrtf(kss[d]), 1e-12f);
            float v = S1[c * 16 + d] / (nq * nk) * t1s;
            vals[d] = v; m = fmaxf(m, v);
        }
        float s = 0.f;
#pragma unroll
        for (int d = 0; d < 16; d++) { vals[d] = expf(vals[d] - m); s += vals[d]; }
#pragma unroll
        for (int d = 0; d < 16; d++)
            am[c * 16 + d] = vals[d] / s * tw2[(h * 16 + c) * 16 + d];
    }
    if (t >= 32 && t < 41) {
        int c = t - 32;
        float nq = fmaxf(sqrtf(qfss[c]), 1e-12f);
        float vr[9], vi[9];
        float mr = -1e30f, mi = -1e30f;
#pragma unroll
        for (int d = 0; d < 9; d++) {
            float nk = fmaxf(sqrtf(kfss[d]), 1e-12f);
            float sc = t2s / (nq * nk);
            vr[d] = Sfr[c * 9 + d] * sc; vi[d] = Sfi[c * 9 + d] * sc;
            mr = fmaxf(mr, vr[d]); mi = fmaxf(mi, vi[d]);
        }
        float sr = 0.f, si = 0.f;
#pragma unroll
        for (int d = 0; d < 9; d++) {
            vr[d] = expf(vr[d] - mr); sr += vr[d];
            vi[d] = expf(vi[d] - mi); si += vi[d];
        }
#pragma unroll
        for (int d = 0; d < 9; d++) {
            float tw = tw1[(h * 9 + c) * 9 + d];
            am[256 + c * 9 + d] = vr[d] / sr * tw;
            am[337 + c * 9 + d] = vi[d] / si * tw;
        }
    }
}

__global__ __launch_bounds__(256) void attn_apply(
    const float* __restrict__ qkv, const float* __restrict__ amats,
    unsigned short* __restrict__ axT)
{
    const int chunk = blockIdx.x, bh = blockIdx.y;
    const int b = bh >> 3, h = bh & 7;
    const int t = threadIdx.x;

    __shared__ float attn1[16][16], ar2[9][9], ai2[9][9];
    __shared__ float ct[9][16], st_[9][16];

    const float* am = amats + (long)bh * 448;
    attn1[t >> 4][t & 15] = am[t];
    if (t < 81) { ar2[t / 9][t % 9] = am[256 + t]; ai2[t / 9][t % 9] = am[337 + t]; }
    if (t < 144) {
        int f = t / 16, c = t % 16;
        float ang = 6.283185307179586f * (float)(f * c) / 16.0f;
        ct[f][c] = cosf(ang);
        st_[f][c] = sinf(ang);
    }
    __syncthreads();

    const int col = chunk * 256 + t;
    const float* vbase = qkv + (long)b * 1572864 + (long)(256 + 16 * h) * 4096;

    float vv[16];
#pragma unroll
    for (int c = 0; c < 16; c++) vv[c] = vbase[(long)c * 4096 + col];

    float o1[16];
#pragma unroll
    for (int m = 0; m < 16; m++) {
        float a = 0.f;
#pragma unroll
        for (int d = 0; d < 16; d++) a += attn1[m][d] * vv[d];
        o1[m] = a;
    }
    float vfr[9], vfi[9];
#pragma unroll
    for (int f = 0; f < 9; f++) {
        float ar = 0.f, ai = 0.f;
#pragma unroll
        for (int c = 0; c < 16; c++) { ar += vv[c] * ct[f][c]; ai -= vv[c] * st_[f][c]; }
        vfr[f] = ar; vfi[f] = ai;
    }
    float Lr[9], Li[9];
#pragma unroll
    for (int c = 0; c < 9; c++) {
        float lr = 0.f, li = 0.f;
#pragma unroll
        for (int d = 0; d < 9; d++) {
            lr += ar2[c][d] * vfr[d] - ai2[c][d] * vfi[d];
            li += ar2[c][d] * vfi[d] + ai2[c][d] * vfr[d];
        }
        Lr[c] = lr; Li[c] = li;
    }
    float lx[16];
#pragma unroll
    for (int m = 0; m < 16; m++) {
        float s = Lr[0] + ((m & 1) ? -Lr[8] : Lr[8]);
#pragma unroll
        for (int f = 1; f < 8; f++)
            s += 2.0f * (Lr[f] * ct[f][m] - Li[f] * st_[f][m]);
        lx[m] = s * 0.0625f;
    }
    unsigned short* op = axT + ((long)b * 4096 + col) * 256;
    store8bf(op + 16 * h,       lx);
    store8bf(op + 16 * h + 8,   lx + 8);
    store8bf(op + 128 + 16 * h,     o1);
    store8bf(op + 128 + 16 * h + 8, o1 + 8);
}

// ---------------------------------------------------------------------------
// Host launch
// ---------------------------------------------------------------------------
extern "C" void kernel_launch(void* const* d_in, const int* in_sizes, int n_in,
                              void* d_out, int out_size, void* d_ws, size_t ws_size,
                              hipStream_t stream)
{
    const float* x          = (const float*)d_in[0];
    const float* pc3a_w     = (const float*)d_in[1];
    const float* hm_conv1_w = (const float*)d_in[2];
    const float* hm_proj2_w = (const float*)d_in[3];
    const float* hm_proj2_b = (const float*)d_in[4];
    const float* pc5_w      = (const float*)d_in[5];
    const float* hm_conv2_w = (const float*)d_in[6];
    const float* fuse_w     = (const float*)d_in[7];
    const float* qkv_pc3_w  = (const float*)d_in[8];
    const float* qkv_w      = (const float*)d_in[9];
    const float* proj_w     = (const float*)d_in[10];
    const float* proj_b     = (const float*)d_in[11];
    const float* temp1      = (const float*)d_in[12];
    const float* temp2      = (const float*)d_in[13];
    const float* tw1        = (const float*)d_in[14];
    const float* tw2        = (const float*)d_in[15];
    float* out = (float*)d_out;
    char* wsb  = (char*)d_ws;

    // ---- workspace layout (bytes) ----
    unsigned short* catT  = (unsigned short*)(wsb + 0);          // 96 MiB (union qkv f32)
    float*          qkv   = (float*)(wsb + 0);
    unsigned short* xT    = (unsigned short*)(wsb + 100663296);  // 32 MiB (union axT)
    unsigned short* axT   = (unsigned short*)(wsb + 100663296);
    unsigned short* hxT   = (unsigned short*)(wsb + 134217728);  // 32 MiB
    unsigned short* y3T   = (unsigned short*)(wsb + 167772160);  //  8 MiB (reused as yqT)
    unsigned short* yqT   = y3T;
    unsigned short* y5T   = (unsigned short*)(wsb + 176160768);  //  8 MiB (union part/amats)
    float*          part  = (float*)(wsb + 176160768);
    float*          amats = (float*)(wsb + 176160768 + 2097152);
    unsigned short* w1b   = (unsigned short*)(wsb + 184549376);
    unsigned short* w2b   = (unsigned short*)(wsb + 184680448);
    unsigned short* w3b   = (unsigned short*)(wsb + 184811520);
    unsigned short* wfb   = (unsigned short*)(wsb + 184942592);
    unsigned short* wqb   = (unsigned short*)(wsb + 185335808);
    unsigned short* wpb   = (unsigned short*)(wsb + 185729024);
    unsigned short* wc3a  = (unsigned short*)(wsb + 185860096);
    unsigned short* wc5   = (unsigned short*)(wsb + 185933824);
    unsigned short* wc3q  = (unsigned short*)(wsb + 186138624);

    dim3 cvg(32, 16);

    // ---- prep (2 merged convert launches + transpose) ----
    cvt_all<<<dim3(768, 6), 256, 0, stream>>>(
        hm_conv1_w, w1b, 65536,
        hm_proj2_w, w2b, 65536,
        hm_conv2_w, w3b, 65536,
        fuse_w,     wfb, 196608,
        qkv_w,      wqb, 196608,
        proj_w,     wpb, 65536);
    cvt_wconv_all<<<dim3(400, 3), 256, 0, stream>>>(
        pc3a_w, wc3a, pc5_w, wc5, qkv_pc3_w, wc3q);
    cvt_xpose<<<dim3(64, 4, 16), 256, 0, stream>>>(x, xT);

    // ---- both branch convs, then ONE merged branch GEMM (3 sels) ----
    conv_mfma<3><<<cvg, 256, 0, stream>>>(xT, 256, wc3a, y3T);
    conv_mfma<5><<<cvg, 256, 0, stream>>>(xT, 256, wc5, y5T);
    {
        GemmP p = {};
        p.sel0 = { y3T,    w1b, nullptr,     64, 0   };
        p.sel1 = { nullptr, w2b, hm_proj2_b,  0, 256 };
        p.sel2 = { y5T,    w3b, nullptr,     64, 512 };
        p.in2T = xT; p.ld2 = 256;
        p.w_ld = 256; p.rowmap = 0; p.otiles = 2; p.K = 256;
        p.mode = 0; p.do_gelu = 1; p.addT = nullptr;
        p.outT = catT; p.ldo = 768; p.outF = nullptr; p.bsF = 0;
        mfma_gemm<<<dim3(32, 6, 16), 256, 0, stream>>>(p);
    }
    // ---- fuse: hxT = fuse_w @ catT + xT (bf16 residual) ----
    {
        GemmP p = {};
        p.sel0 = { nullptr, wfb, nullptr, 0, 0 };
        p.in2T = catT; p.ld2 = 768;
        p.w_ld = 768; p.rowmap = 0; p.otiles = 2; p.K = 768;
        p.mode = 0; p.do_gelu = 0; p.addT = xT;
        p.outT = hxT; p.ldo = 256; p.outF = nullptr; p.bsF = 0;
        mfma_gemm<<<dim3(32, 2, 16), 256, 0, stream>>>(p);
    }
    // ---- qkv = qkv_w'[384 rows] @ [conv3(hx[:64]); hx[64:]] (f32 ch-major) ----
    conv_mfma<3><<<cvg, 256, 0, stream>>>(hxT, 256, wc3q, yqT);
    {
        GemmP p = {};
        p.sel0 = { yqT, wqb, nullptr, 64, 0 };
        p.in2T = hxT; p.ld2 = 256;
        p.w_ld = 256; p.rowmap = 1; p.otiles = 3; p.K = 256;
        p.mode = 1; p.do_gelu = 0; p.addT = nullptr;
        p.outT = nullptr; p.ldo = 0; p.outF = qkv; p.bsF = 1572864L;
        mfma_gemm<<<dim3(32, 3, 16), 256, 0, stream>>>(p);
    }
    // ---- attention ----
    attn_reduce<<<dim3(8, 128), 256, 0, stream>>>(qkv, part);
    attn_mats<<<128, 256, 0, stream>>>(part, temp1, temp2, tw1, tw2, amats);
    attn_apply<<<dim3(16, 128), 256, 0, stream>>>(qkv, amats, axT);
    // ---- out = proj_w @ axT + proj_b (f32 ch-major) ----
    {
        GemmP p = {};
        p.sel0 = { nullptr, wpb, proj_b, 0, 0 };
        p.in2T = axT; p.ld2 = 256;
        p.w_ld = 256; p.rowmap = 0; p.otiles = 2; p.K = 256;
        p.mode = 1; p.do_gelu = 0; p.addT = nullptr;
        p.outT = nullptr; p.ldo = 0; p.outF = out; p.bsF = 1048576L;
        mfma_gemm<<<dim3(32, 2, 16), 256, 0, stream>>>(p);
    }
}

// Round 11
// 400.032 us; speedup vs baseline: 1.0371x; 1.0371x over previous
//
#include <hip/hip_runtime.h>
#include <math.h>

// ---------------------------------------------------------------------------
// Problem constants: B=16, DIM=256, H=W=64, HEADS=8, C2=16, CF=9, DC=64
// Activations for MFMA are TOKEN-major bf16 [b][4096][C] (K-contiguous).
// f32 kept only for: x (input), qkv (attention), final out.
// ---------------------------------------------------------------------------

typedef __attribute__((ext_vector_type(8))) short bf16x8;
typedef __attribute__((ext_vector_type(4))) float f32x4;

__device__ __forceinline__ float gelu_f(float v) {
    // tanh-form GELU: max abs dev from exact (erf) form ~3e-4; pre-activations
    // here have sigma~0.32 so typical dev <1e-4. ~10 VALU ops vs ~50 for erff
    // (erff was 37% VALUBusy on the branch GEMM, r10 PMC).
    float u = v * (0.7978845608f + 0.0356774081f * v * v);
    u = fminf(fmaxf(u, -10.f), 10.f);
    float t = __expf(2.0f * u);            // v_exp_f32 path
    float th = (t - 1.0f) / (t + 1.0f);
    return 0.5f * v * (1.0f + th);
}
__device__ __forceinline__ unsigned short f2bf(float f) {
    unsigned u = __builtin_bit_cast(unsigned, f);
    u += 0x7fffu + ((u >> 16) & 1u);
    return (unsigned short)(u >> 16);
}
__device__ __forceinline__ float bf2f(unsigned short h) {
    return __builtin_bit_cast(float, (unsigned)h << 16);
}
__device__ __forceinline__ void store8bf(unsigned short* p, const float* v) {
    unsigned short h[8];
#pragma unroll
    for (int i = 0; i < 8; i++) h[i] = f2bf(v[i]);
    uint4 o;
    o.x = h[0] | ((unsigned)h[1] << 16);
    o.y = h[2] | ((unsigned)h[3] << 16);
    o.z = h[4] | ((unsigned)h[5] << 16);
    o.w = h[6] | ((unsigned)h[7] << 16);
    *(uint4*)p = o;
}

// global -> LDS direct 16B async copy (wave-uniform LDS base, lane scatter i*16)
typedef __attribute__((address_space(1))) void gvoid;
typedef __attribute__((address_space(3))) void svoid;
__device__ __forceinline__ void gl_lds16(const unsigned short* g, unsigned short* l) {
    __builtin_amdgcn_global_load_lds((gvoid*)g, (svoid*)l, 16, 0, 0);
}

// ---------------------------------------------------------------------------
// Merged f32 -> bf16 weight converts (6 segments, one launch)
// ---------------------------------------------------------------------------
__global__ __launch_bounds__(256) void cvt_all(
    const float* __restrict__ a0, unsigned short* __restrict__ d0, int m0,
    const float* __restrict__ a1, unsigned short* __restrict__ d1, int m1,
    const float* __restrict__ a2, unsigned short* __restrict__ d2, int m2,
    const float* __restrict__ a3, unsigned short* __restrict__ d3, int m3,
    const float* __restrict__ a4, unsigned short* __restrict__ d4, int m4,
    const float* __restrict__ a5, unsigned short* __restrict__ d5, int m5)
{
    int sy = blockIdx.y;
    int i = blockIdx.x * 256 + threadIdx.x;
    const float* s; unsigned short* d; int n;
    if      (sy == 0) { s = a0; d = d0; n = m0; }
    else if (sy == 1) { s = a1; d = d1; n = m1; }
    else if (sy == 2) { s = a2; d = d2; n = m2; }
    else if (sy == 3) { s = a3; d = d3; n = m3; }
    else if (sy == 4) { s = a4; d = d4; n = m4; }
    else              { s = a5; d = d5; n = m5; }
    if (i < n) d[i] = f2bf(s[i]);
}

// ---------------------------------------------------------------------------
// Merged conv-weight converts OIHW f32 -> bf16 [tap][oc][ic] (3 segments)
// ---------------------------------------------------------------------------
__global__ __launch_bounds__(256) void cvt_wconv_all(
    const float* __restrict__ w0, unsigned short* __restrict__ o0,
    const float* __restrict__ w1, unsigned short* __restrict__ o1,
    const float* __restrict__ w2, unsigned short* __restrict__ o2)
{
    int sy = blockIdx.y;
    const float* w; unsigned short* wb; int KK;
    if      (sy == 0) { w = w0; wb = o0; KK = 9;  }
    else if (sy == 1) { w = w1; wb = o1; KK = 25; }
    else              { w = w2; wb = o2; KK = 9;  }
    int idx = blockIdx.x * 256 + threadIdx.x;
    if (idx >= 64 * 64 * KK) return;
    int ic = idx & 63, oc = (idx >> 6) & 63, tap = idx >> 12;
    wb[tap * 4096 + oc * 64 + ic] = f2bf(w[(oc * 64 + ic) * KK + tap]);
}

// ---------------------------------------------------------------------------
// x [b][256][4096] f32 -> xT [b][4096][256] bf16 (LDS tile transpose)
// ---------------------------------------------------------------------------
__global__ __launch_bounds__(256) void cvt_xpose(
    const float* __restrict__ x, unsigned short* __restrict__ xT)
{
    __shared__ float tile[64][65];
    const int t = threadIdx.x;
    const int n0 = blockIdx.x * 64, c0 = blockIdx.y * 64, b = blockIdx.z;
    const float* xb = x + (long)b * 1048576;
#pragma unroll
    for (int i = 0; i < 16; i++) {
        int c = i * 4 + (t >> 6), n = t & 63;
        tile[c][n] = xb[(long)(c0 + c) * 4096 + n0 + n];
    }
    __syncthreads();
    unsigned short* xTb = xT + (long)b * 4096 * 256;
#pragma unroll
    for (int i = 0; i < 4; i++) {
        int n = i * 16 + (t >> 4), cc = (t & 15) * 4;
        unsigned short h0 = f2bf(tile[cc + 0][n]);
        unsigned short h1 = f2bf(tile[cc + 1][n]);
        unsigned short h2 = f2bf(tile[cc + 2][n]);
        unsigned short h3 = f2bf(tile[cc + 3][n]);
        uint2 val;
        val.x = h0 | ((unsigned)h1 << 16);
        val.y = h2 | ((unsigned)h3 << 16);
        *(uint2*)&xTb[(long)(n0 + n) * 256 + c0 + cc] = val;
    }
}

// ---------------------------------------------------------------------------
// MFMA bf16 GEMM v5 = v4 + segment-XOR LDS swizzle (both-sides, rule #21):
// gl_lds dest stays linear; lane l's GLOBAL source fetches 16B-segment
// (l&3)^((l>>2)&3) of its row; ds_read uses seg (fq ^ (fr&3)). Breaks the
// 8-way bank conflict of linear 64B rows down to 4-way.
// ---------------------------------------------------------------------------
#define LDW 32

struct GSel {
    const unsigned short* in1;   // cols [0,c1) source (ld 64), may be null
    const unsigned short* W;     // weights, ld w_ld
    const float* bias;           // may be null
    int c1;
    int col_off;                 // outT column offset
};
struct GemmP {
    GSel sel0, sel1, sel2;
    const unsigned short* in2T;  // cols [c1,K) source (absolute col)
    long ld2;
    int w_ld, rowmap, otiles, K, mode, do_gelu;
    const unsigned short* addT;  // token-major bf16 residual (ld 256), may be null
    unsigned short* outT;        // token-major bf16 out
    int ldo;
    float* outF;                 // channel-major f32 out
    long bsF;
};

__global__ __launch_bounds__(256) void mfma_gemm(GemmP p)
{
    __shared__ unsigned short SM[16384];  // 32 KB: A at [buf*4096], B at [8192+buf*4096]
    const int t = threadIdx.x, b = blockIdx.z;
    const int n0 = blockIdx.x * 128;
    const unsigned sy = blockIdx.y;
    const int s  = sy / (unsigned)p.otiles;
    const int ot = sy % (unsigned)p.otiles;
    GSel g = p.sel0;
    if (s == 1) g = p.sel1;
    else if (s == 2) g = p.sel2;
    const int o0 = ot * 128;
    const int w = t >> 6, l = t & 63;
    const int fr = l & 15, fq = l >> 4;
    const int wr = (w >> 1) * 64, wc = (w & 1) * 64;
    const int lrow = l >> 2;
    // source-side segment swizzle: lane l fetches seg (l&3)^(row&3) of its row
    const int lcol = (((l & 3) ^ (lrow & 3)) * 8);

    // staging geometry: wave w owns LDS rows [32w,32w+16) and [32w+16,32w+32)
    const int ta0 = 32 * w + lrow, ta1 = ta0 + 16;
    int ra0 = o0 + ta0, ra1 = o0 + ta1;
    if (p.rowmap) {
        ra0 = ((ra0 >> 7) << 8) + (((ra0 >> 4) & 7) << 5) + 16 + (ra0 & 15);
        ra1 = ((ra1 >> 7) << 8) + (((ra1 >> 4) & 7) << 5) + 16 + (ra1 & 15);
    }
    const unsigned short* Ag0 = g.W + (long)ra0 * p.w_ld + lcol;
    const unsigned short* Ag1 = g.W + (long)ra1 * p.w_ld + lcol;
    const unsigned short* i1b = g.in1 ? g.in1 : p.in2T;
    const unsigned short* i1r0 = i1b + ((long)b * 4096 + n0 + ta0) * 64 + lcol;
    const unsigned short* i1r1 = i1r0 + 16L * 64;
    const unsigned short* i2r0 = p.in2T + ((long)b * 4096 + n0 + ta0) * p.ld2 + lcol;
    const unsigned short* i2r1 = i2r0 + 16L * p.ld2;

#define STAGE(BUF, KK) do {                                                    \
        gl_lds16(Ag0 + (KK), &SM[(BUF) * 4096 + (32 * w) * LDW]);              \
        gl_lds16(Ag1 + (KK), &SM[(BUF) * 4096 + (32 * w + 16) * LDW]);         \
        if ((KK) < g.c1) {                                                     \
            gl_lds16(i1r0 + (KK), &SM[8192 + (BUF) * 4096 + (32 * w) * LDW]);  \
            gl_lds16(i1r1 + (KK), &SM[8192 + (BUF) * 4096 + (32 * w + 16) * LDW]); \
        } else {                                                               \
            gl_lds16(i2r0 + (KK), &SM[8192 + (BUF) * 4096 + (32 * w) * LDW]);  \
            gl_lds16(i2r1 + (KK), &SM[8192 + (BUF) * 4096 + (32 * w + 16) * LDW]); \
        } } while (0)

    f32x4 acc[4][4];
#pragma unroll
    for (int m = 0; m < 4; m++)
#pragma unroll
        for (int n = 0; n < 4; n++) acc[m][n] = (f32x4){0.f, 0.f, 0.f, 0.f};

    STAGE(0, 0);
    __syncthreads();

    // read-side swizzle: want global seg fq of row R -> LDS seg fq^(R&3);
    // R&3 == fr&3 for all fragment rows (wr/wc/m*16/n*16 are multiples of 4)
    const int sseg = (fq ^ (fr & 3)) * 8;

    const int NK = p.K >> 5;
    for (int ks = 0; ks < NK; ks++) {
        const int cur = ks & 1;
        const int kn = (ks + 1) << 5;
        if (kn < p.K) STAGE(cur ^ 1, kn);      // async into other buffer
        bf16x8 af[4], bv[4];
#pragma unroll
        for (int m = 0; m < 4; m++)
            af[m] = *(const bf16x8*)&SM[cur * 4096 + (wr + m * 16 + fr) * LDW + sseg];
#pragma unroll
        for (int n = 0; n < 4; n++)
            bv[n] = *(const bf16x8*)&SM[8192 + cur * 4096 + (wc + n * 16 + fr) * LDW + sseg];
#pragma unroll
        for (int m = 0; m < 4; m++)
#pragma unroll
            for (int n = 0; n < 4; n++)
                acc[m][n] = __builtin_amdgcn_mfma_f32_16x16x32_bf16(af[m], bv[n], acc[m][n], 0, 0, 0);
        __syncthreads();                        // drains vmcnt (stage done) + lgkm
    }
#undef STAGE

    // ---- epilogue ----
    if (p.mode == 0) {
        // LDS-staged coalesced store: two passes of 64 tokens, tile [64][136].
#define EPW 136
#pragma unroll
        for (int pass = 0; pass < 2; pass++) {
            if ((w & 1) == pass) {               // waves whose wc == 64*pass
#pragma unroll
                for (int m = 0; m < 4; m++) {
                    int chm = wr + m * 16 + fq * 4;     // local channel 0..127
                    int ob = o0 + chm;
                    float bm[4] = {0.f, 0.f, 0.f, 0.f};
                    if (g.bias) {
#pragma unroll
                        for (int r = 0; r < 4; r++) bm[r] = g.bias[ob + r];
                    }
#pragma unroll
                    for (int n = 0; n < 4; n++) {
                        int tn = n * 16 + fr;            // local token 0..63
                        int ng = n0 + pass * 64 + tn;
                        float e[4];
#pragma unroll
                        for (int r = 0; r < 4; r++) {
                            e[r] = acc[m][n][r] + bm[r];
                            if (p.do_gelu) e[r] = gelu_f(e[r]);
                        }
                        if (p.addT) {
                            uint2 av = *(const uint2*)&p.addT[((long)b * 4096 + ng) * 256 + ob];
                            e[0] += bf2f((unsigned short)(av.x & 0xffff));
                            e[1] += bf2f((unsigned short)(av.x >> 16));
                            e[2] += bf2f((unsigned short)(av.y & 0xffff));
                            e[3] += bf2f((unsigned short)(av.y >> 16));
                        }
                        unsigned short h[4];
#pragma unroll
                        for (int r = 0; r < 4; r++) h[r] = f2bf(e[r]);
                        uint2 val;
                        val.x = h[0] | ((unsigned)h[1] << 16);
                        val.y = h[2] | ((unsigned)h[3] << 16);
                        *(uint2*)&SM[tn * EPW + chm] = val;
                    }
                }
            }
            __syncthreads();
            // readout: 1024 x 16B chunks; 16 chunks per token row (256 B)
#pragma unroll
            for (int i = 0; i < 4; i++) {
                int c = t + i * 256;
                int tn = c >> 4, pos = c & 15;
                uint4 v = *(const uint4*)&SM[tn * EPW + pos * 8];
                *(uint4*)&p.outT[((long)b * 4096 + n0 + pass * 64 + tn) * (long)p.ldo
                                 + g.col_off + o0 + pos * 8] = v;
            }
            __syncthreads();
        }
#undef EPW
    } else {
        // f32 channel-major epilogue (qkv / proj / out)
#pragma unroll
        for (int m = 0; m < 4; m++) {
            int ob = o0 + wr + m * 16 + fq * 4;
            float bm[4] = {0.f, 0.f, 0.f, 0.f};
            if (g.bias) {
#pragma unroll
                for (int r = 0; r < 4; r++) bm[r] = g.bias[ob + r];
            }
#pragma unroll
            for (int n = 0; n < 4; n++) {
                int ng = n0 + wc + n * 16 + fr;
                float e[4];
#pragma unroll
                for (int r = 0; r < 4; r++) {
                    e[r] = acc[m][n][r] + bm[r];
                    if (p.do_gelu) e[r] = gelu_f(e[r]);
                }
#pragma unroll
                for (int r = 0; r < 4; r++)
                    p.outF[(long)b * p.bsF + (long)(ob + r) * 4096 + ng] = e[r];
            }
        }
    }
}

// ---------------------------------------------------------------------------
// MFMA conv (unchanged — passed).
// ---------------------------------------------------------------------------
template<int K>
__global__ __launch_bounds__(256) void conv_mfma(
    const unsigned short* __restrict__ inT, int ldin,
    const unsigned short* __restrict__ wb,
    unsigned short* __restrict__ outT)
{
    constexpr int R   = K / 2;
    constexpr int NR  = 2 + 2 * R;
    constexpr int W   = 64 + 2 * R;
    constexpr int ICP = 40;
    __shared__ unsigned short lds[NR * W * ICP];
    const int t = threadIdx.x;
    const int b = blockIdx.y;
    const int y0 = blockIdx.x * 2;
    const int w = t >> 6, l = t & 63;
    const int fr = l & 15, fq = l >> 4;
    const int ocw = (w & 1) * 32;
    const int rw  = w >> 1;

    f32x4 acc[2][4];
#pragma unroll
    for (int m = 0; m < 2; m++)
#pragma unroll
        for (int j = 0; j < 4; j++) acc[m][j] = (f32x4){0.f, 0.f, 0.f, 0.f};

    for (int kk = 0; kk < 64; kk += 32) {
        __syncthreads();
        for (int e = t; e < NR * W * 4; e += 256) {
            int part = e & 3;
            int px   = (e >> 2) % W;
            int row  = (e >> 2) / W;
            int gx = px - R, gy = y0 - R + row;
            uint4 v = {0u, 0u, 0u, 0u};
            if ((unsigned)gx < 64u && (unsigned)gy < 64u)
                v = *(const uint4*)&inT[((long)b * 4096 + gy * 64 + gx) * (long)ldin + kk + part * 8];
            *(uint4*)&lds[(row * W + px) * ICP + part * 8] = v;
        }
        __syncthreads();
#pragma unroll
        for (int ky = 0; ky < K; ky++) {
#pragma unroll
            for (int kx = 0; kx < K; kx++) {
                const unsigned short* wt = wb + ((long)((ky * K + kx) * 64 + ocw)) * 64 + kk;
                bf16x8 aw0 = *(const bf16x8*)&wt[fr * 64 + fq * 8];
                bf16x8 aw1 = *(const bf16x8*)&wt[(16 + fr) * 64 + fq * 8];
                const unsigned short* lp = &lds[((rw + ky) * W + kx) * ICP + fq * 8];
#pragma unroll
                for (int j = 0; j < 4; j++) {
                    bf16x8 bt = *(const bf16x8*)&lp[(j * 16 + fr) * ICP];
                    acc[0][j] = __builtin_amdgcn_mfma_f32_16x16x32_bf16(aw0, bt, acc[0][j], 0, 0, 0);
                    acc[1][j] = __builtin_amdgcn_mfma_f32_16x16x32_bf16(aw1, bt, acc[1][j], 0, 0, 0);
                }
            }
        }
    }
    const long tokbase = (long)b * 4096 + (y0 + rw) * 64;
#pragma unroll
    for (int mi = 0; mi < 2; mi++) {
        int oc0 = ocw + mi * 16 + fq * 4;
#pragma unroll
        for (int j = 0; j < 4; j++) {
            long tok = tokbase + j * 16 + fr;
            unsigned short h[4];
#pragma unroll
            for (int r = 0; r < 4; r++) h[r] = f2bf(acc[mi][j][r]);
            uint2 val;
            val.x = h[0] | ((unsigned)h[1] << 16);
            val.y = h[2] | ((unsigned)h[3] << 16);
            *(uint2*)&outT[tok * 64 + oc0] = val;
        }
    }
}

// ---------------------------------------------------------------------------
// Attention (f32, unchanged): reduce -> mats -> apply.
// ---------------------------------------------------------------------------
#define NC 128
#define ST 132

__global__ __launch_bounds__(256) void attn_reduce(
    const float* __restrict__ qkv, float* __restrict__ part)
{
    const int chunk = blockIdx.x, bh = blockIdx.y;
    const int b = bh >> 3, h = bh & 7;
    const int t = threadIdx.x;

    __shared__ float qch[16][ST], kch[16][ST];
    __shared__ float qfr[9][ST], qfi[9][ST], kfr[9][ST], kfi[9][ST];
    __shared__ float ct[9][16], st_[9][16];

    if (t < 144) {
        int f = t / 16, c = t % 16;
        float ang = 6.283185307179586f * (float)(f * c) / 16.0f;
        ct[f][c] = cosf(ang);
        st_[f][c] = sinf(ang);
    }

    const float* qbase = qkv + (long)b * 1572864 + (long)(16 * h) * 4096;
    const float* kbase = qbase + 128 * 4096;

    float s1 = 0.f, sfr = 0.f, sfi = 0.f;
    float qssp = 0.f, kssp = 0.f, qfssp = 0.f, kfssp = 0.f;
    const int c0 = t >> 4, d0 = t & 15;
    const int cf = t / 9, df = t % 9;
    const int rr = t >> 4, jj0 = t & 15;

    const int nlo = chunk * 512, nhi = nlo + 512;
    for (int n0 = nlo; n0 < nhi; n0 += NC) {
        __syncthreads();
#pragma unroll
        for (int i = 0; i < 8; i++) {
            int e = i * 256 + t, row = e >> 7, nn = e & 127;
            qch[row][nn] = qbase[(long)row * 4096 + n0 + nn];
            kch[row][nn] = kbase[(long)row * 4096 + n0 + nn];
        }
        __syncthreads();
        {
            int col = t & 127;
            bool isq = t < 128;
            float vv[16];
#pragma unroll
            for (int c = 0; c < 16; c++) vv[c] = isq ? qch[c][col] : kch[c][col];
#pragma unroll
            for (int f = 0; f < 9; f++) {
                float ar = 0.f, ai = 0.f;
#pragma unroll
                for (int c = 0; c < 16; c++) { ar += vv[c] * ct[f][c]; ai -= vv[c] * st_[f][c]; }
                if (isq) { qfr[f][col] = ar; qfi[f][col] = ai; }
                else     { kfr[f][col] = ar; kfi[f][col] = ai; }
            }
        }
#pragma unroll 4
        for (int n = 0; n < NC; n++) s1 += qch[c0][n] * kch[d0][n];
        for (int n = jj0; n < NC; n += 16) {
            float a = qch[rr][n]; qssp += a * a;
            float bq = kch[rr][n]; kssp += bq * bq;
        }
        __syncthreads();
        if (t < 81) {
#pragma unroll 4
            for (int n = 0; n < NC; n++) {
                float qr = qfr[cf][n], qi = qfi[cf][n];
                float kr = kfr[df][n], ki = kfi[df][n];
                sfr += qr * kr - qi * ki;
                sfi += qr * ki + qi * kr;
            }
        }
        if (t < 144) {
            int f = t >> 4;
            for (int n = jj0; n < NC; n += 16) {
                qfssp += qfr[f][n] * qfr[f][n] + qfi[f][n] * qfi[f][n];
                kfssp += kfr[f][n] * kfr[f][n] + kfi[f][n] * kfi[f][n];
            }
        }
    }

#pragma unroll
    for (int off = 8; off; off >>= 1) {
        qssp  += __shfl_xor(qssp, off);
        kssp  += __shfl_xor(kssp, off);
        qfssp += __shfl_xor(qfssp, off);
        kfssp += __shfl_xor(kfssp, off);
    }
    float* pb = part + (long)(bh * 8 + chunk) * 512;
    pb[t] = s1;
    if (t < 81) { pb[256 + t] = sfr; pb[337 + t] = sfi; }
    if (jj0 == 0) { pb[448 + rr] = qssp; pb[464 + rr] = kssp; }
    if (jj0 == 0 && t < 144) { pb[480 + rr] = qfssp; pb[489 + rr] = kfssp; }
}

__global__ __launch_bounds__(256) void attn_mats(
    const float* __restrict__ part,
    const float* __restrict__ temp1, const float* __restrict__ temp2,
    const float* __restrict__ tw1, const float* __restrict__ tw2,
    float* __restrict__ amats)
{
    const int bh = blockIdx.x;
    const int h = bh & 7;
    const int t = threadIdx.x;

    __shared__ float S1[256], Sfr[81], Sfi[81];
    __shared__ float qss[16], kss[16], qfss[9], kfss[9];

    float s1 = 0.f, sfr = 0.f, sfi = 0.f, a0 = 0.f, a1 = 0.f, a2 = 0.f, a3 = 0.f;
#pragma unroll
    for (int ch = 0; ch < 8; ch++) {
        const float* p = part + (long)(bh * 8 + ch) * 512;
        s1 += p[t];
        if (t < 81) { sfr += p[256 + t]; sfi += p[337 + t]; }
        if (t < 16) { a0 += p[448 + t]; a1 += p[464 + t]; }
        if (t < 9)  { a2 += p[480 + t]; a3 += p[489 + t]; }
    }
    S1[t] = s1;
    if (t < 81) { Sfr[t] = sfr; Sfi[t] = sfi; }
    if (t < 16) { qss[t] = a0; kss[t] = a1; }
    if (t < 9)  { qfss[t] = a2; kfss[t] = a3; }
    __syncthreads();

    const float t1s = temp1[h], t2s = temp2[h];
    float* am = amats + (long)bh * 448;
    if (t < 16) {
        int c = t;
        float nq = fmaxf(sqrtf(qss[c]), 1e-12f);
        float vals[16];
        float m = -1e30f;
#pragma unroll
        for (int d = 0; d < 16; d++) {
            float nk = fmaxf(sqrtf(kss[d]), 1e-12f);
            float v = S1[c * 16 + d] / (nq * nk) * t1s;
            vals[d] = v; m = fmaxf(m, v);
        }
        float s = 0.f;
#pragma unroll
        for (int d = 0; d < 16; d++) { vals[d] = expf(vals[d] - m); s += vals[d]; }
#pragma unroll
        for (int d = 0; d < 16; d++)
            am[c * 16 + d] = vals[d] / s * tw2[(h * 16 + c) * 16 + d];
    }
    if (t >= 32 && t < 41) {
        int c = t - 32;
        float nq = fmaxf(sqrtf(qfss[c]), 1e-12f);
        float vr[9], vi[9];
        float mr = -1e30f, mi = -1e30f;
#pragma unroll
        for (int d = 0; d < 9; d++) {
            float nk = fmaxf(sqrtf(kfss[d]), 1e-12f);
            float sc = t2s / (nq * nk);
            vr[d] = Sfr[c * 9 + d] * sc; vi[d] = Sfi[c * 9 + d] * sc;
            mr = fmaxf(mr, vr[d]); mi = fmaxf(mi, vi[d]);
        }
        float sr = 0.f, si = 0.f;
#pragma unroll
        for (int d = 0; d < 9; d++) {
            vr[d] = expf(vr[d] - mr); sr += vr[d];
            vi[d] = expf(vi[d] - mi); si += vi[d];
        }
#pragma unroll
        for (int d = 0; d < 9; d++) {
            float tw = tw1[(h * 9 + c) * 9 + d];
            am[256 + c * 9 + d] = vr[d] / sr * tw;
            am[337 + c * 9 + d] = vi[d] / si * tw;
        }
    }
}

__global__ __launch_bounds__(256) void attn_apply(
    const float* __restrict__ qkv, const float* __restrict__ amats,
    unsigned short* __restrict__ axT)
{
    const int chunk = blockIdx.x, bh = blockIdx.y;
    const int b = bh >> 3, h = bh & 7;
    const int t = threadIdx.x;

    __shared__ float attn1[16][16], ar2[9][9], ai2[9][9];
    __shared__ float ct[9][16], st_[9][16];

    const float* am = amats + (long)bh * 448;
    attn1[t >> 4][t & 15] = am[t];
    if (t < 81) { ar2[t / 9][t % 9] = am[256 + t]; ai2[t / 9][t % 9] = am[337 + t]; }
    if (t < 144) {
        int f = t / 16, c = t % 16;
        float ang = 6.283185307179586f * (float)(f * c) / 16.0f;
        ct[f][c] = cosf(ang);
        st_[f][c] = sinf(ang);
    }
    __syncthreads();

    const int col = chunk * 256 + t;
    const float* vbase = qkv + (long)b * 1572864 + (long)(256 + 16 * h) * 4096;

    float vv[16];
#pragma unroll
    for (int c = 0; c < 16; c++) vv[c] = vbase[(long)c * 4096 + col];

    float o1[16];
#pragma unroll
    for (int m = 0; m < 16; m++) {
        float a = 0.f;
#pragma unroll
        for (int d = 0; d < 16; d++) a += attn1[m][d] * vv[d];
        o1[m] = a;
    }
    float vfr[9], vfi[9];
#pragma unroll
    for (int f = 0; f < 9; f++) {
        float ar = 0.f, ai = 0.f;
#pragma unroll
        for (int c = 0; c < 16; c++) { ar += vv[c] * ct[f][c]; ai -= vv[c] * st_[f][c]; }
        vfr[f] = ar; vfi[f] = ai;
    }
    float Lr[9], Li[9];
#pragma unroll
    for (int c = 0; c < 9; c++) {
        float lr = 0.f, li = 0.f;
#pragma unroll
        for (int d = 0; d < 9; d++) {
            lr += ar2[c][d] * vfr[d] - ai2[c][d] * vfi[d];
            li += ar2[c][d] * vfi[d] + ai2[c][d] * vfr[d];
        }
        Lr[c] = lr; Li[c] = li;
    }
    float lx[16];
#pragma unroll
    for (int m = 0; m < 16; m++) {
        float s = Lr[0] + ((m & 1) ? -Lr[8] : Lr[8]);
#pragma unroll
        for (int f = 1; f < 8; f++)
            s += 2.0f * (Lr[f] * ct[f][m] - Li[f] * st_[f][m]);
        lx[m] = s * 0.0625f;
    }
    unsigned short* op = axT + ((long)b * 4096 + col) * 256;
    store8bf(op + 16 * h,       lx);
    store8bf(op + 16 * h + 8,   lx + 8);
    store8bf(op + 128 + 16 * h,     o1);
    store8bf(op + 128 + 16 * h + 8, o1 + 8);
}

// ---------------------------------------------------------------------------
// Host launch
// ---------------------------------------------------------------------------
extern "C" void kernel_launch(void* const* d_in, const int* in_sizes, int n_in,
                              void* d_out, int out_size, void* d_ws, size_t ws_size,
                              hipStream_t stream)
{
    const float* x          = (const float*)d_in[0];
    const float* pc3a_w     = (const float*)d_in[1];
    const float* hm_conv1_w = (const float*)d_in[2];
    const float* hm_proj2_w = (const float*)d_in[3];
    const float* hm_proj2_b = (const float*)d_in[4];
    const float* pc5_w      = (const float*)d_in[5];
    const float* hm_conv2_w = (const float*)d_in[6];
    const float* fuse_w     = (const float*)d_in[7];
    const float* qkv_pc3_w  = (const float*)d_in[8];
    const float* qkv_w      = (const float*)d_in[9];
    const float* proj_w     = (const float*)d_in[10];
    const float* proj_b     = (const float*)d_in[11];
    const float* temp1      = (const float*)d_in[12];
    const float* temp2      = (const float*)d_in[13];
    const float* tw1        = (const float*)d_in[14];
    const float* tw2        = (const float*)d_in[15];
    float* out = (float*)d_out;
    char* wsb  = (char*)d_ws;

    // ---- workspace layout (bytes) ----
    unsigned short* catT  = (unsigned short*)(wsb + 0);          // 96 MiB (union qkv f32)
    float*          qkv   = (float*)(wsb + 0);
    unsigned short* xT    = (unsigned short*)(wsb + 100663296);  // 32 MiB (union axT)
    unsigned short* axT   = (unsigned short*)(wsb + 100663296);
    unsigned short* hxT   = (unsigned short*)(wsb + 134217728);  // 32 MiB
    unsigned short* y3T   = (unsigned short*)(wsb + 167772160);  //  8 MiB (reused as yqT)
    unsigned short* yqT   = y3T;
    unsigned short* y5T   = (unsigned short*)(wsb + 176160768);  //  8 MiB (union part/amats)
    float*          part  = (float*)(wsb + 176160768);
    float*          amats = (float*)(wsb + 176160768 + 2097152);
    unsigned short* w1b   = (unsigned short*)(wsb + 184549376);
    unsigned short* w2b   = (unsigned short*)(wsb + 184680448);
    unsigned short* w3b   = (unsigned short*)(wsb + 184811520);
    unsigned short* wfb   = (unsigned short*)(wsb + 184942592);
    unsigned short* wqb   = (unsigned short*)(wsb + 185335808);
    unsigned short* wpb   = (unsigned short*)(wsb + 185729024);
    unsigned short* wc3a  = (unsigned short*)(wsb + 185860096);
    unsigned short* wc5   = (unsigned short*)(wsb + 185933824);
    unsigned short* wc3q  = (unsigned short*)(wsb + 186138624);

    dim3 cvg(32, 16);

    // ---- prep (2 merged convert launches + transpose) ----
    cvt_all<<<dim3(768, 6), 256, 0, stream>>>(
        hm_conv1_w, w1b, 65536,
        hm_proj2_w, w2b, 65536,
        hm_conv2_w, w3b, 65536,
        fuse_w,     wfb, 196608,
        qkv_w,      wqb, 196608,
        proj_w,     wpb, 65536);
    cvt_wconv_all<<<dim3(400, 3), 256, 0, stream>>>(
        pc3a_w, wc3a, pc5_w, wc5, qkv_pc3_w, wc3q);
    cvt_xpose<<<dim3(64, 4, 16), 256, 0, stream>>>(x, xT);

    // ---- both branch convs, then ONE merged branch GEMM (3 sels) ----
    conv_mfma<3><<<cvg, 256, 0, stream>>>(xT, 256, wc3a, y3T);
    conv_mfma<5><<<cvg, 256, 0, stream>>>(xT, 256, wc5, y5T);
    {
        GemmP p = {};
        p.sel0 = { y3T,    w1b, nullptr,     64, 0   };
        p.sel1 = { nullptr, w2b, hm_proj2_b,  0, 256 };
        p.sel2 = { y5T,    w3b, nullptr,     64, 512 };
        p.in2T = xT; p.ld2 = 256;
        p.w_ld = 256; p.rowmap = 0; p.otiles = 2; p.K = 256;
        p.mode = 0; p.do_gelu = 1; p.addT = nullptr;
        p.outT = catT; p.ldo = 768; p.outF = nullptr; p.bsF = 0;
        mfma_gemm<<<dim3(32, 6, 16), 256, 0, stream>>>(p);
    }
    // ---- fuse: hxT = fuse_w @ catT + xT (bf16 residual) ----
    {
        GemmP p = {};
        p.sel0 = { nullptr, wfb, nullptr, 0, 0 };
        p.in2T = catT; p.ld2 = 768;
        p.w_ld = 768; p.rowmap = 0; p.otiles = 2; p.K = 768;
        p.mode = 0; p.do_gelu = 0; p.addT = xT;
        p.outT = hxT; p.ldo = 256; p.outF = nullptr; p.bsF = 0;
        mfma_gemm<<<dim3(32, 2, 16), 256, 0, stream>>>(p);
    }
    // ---- qkv = qkv_w'[384 rows] @ [conv3(hx[:64]); hx[64:]] (f32 ch-major) ----
    conv_mfma<3><<<cvg, 256, 0, stream>>>(hxT, 256, wc3q, yqT);
    {
        GemmP p = {};
        p.sel0 = { yqT, wqb, nullptr, 64, 0 };
        p.in2T = hxT; p.ld2 = 256;
        p.w_ld = 256; p.rowmap = 1; p.otiles = 3; p.K = 256;
        p.mode = 1; p.do_gelu = 0; p.addT = nullptr;
        p.outT = nullptr; p.ldo = 0; p.outF = qkv; p.bsF = 1572864L;
        mfma_gemm<<<dim3(32, 3, 16), 256, 0, stream>>>(p);
    }
    // ---- attention ----
    attn_reduce<<<dim3(8, 128), 256, 0, stream>>>(qkv, part);
    attn_mats<<<128, 256, 0, stream>>>(part, temp1, temp2, tw1, tw2, amats);
    attn_apply<<<dim3(16, 128), 256, 0, stream>>>(qkv, amats, axT);
    // ---- out = proj_w @ axT + proj_b (f32 ch-major) ----
    {
        GemmP p = {};
        p.sel0 = { nullptr, wpb, proj_b, 0, 0 };
        p.in2T = axT; p.ld2 = 256;
        p.w_ld = 256; p.rowmap = 0; p.otiles = 2; p.K = 256;
        p.mode = 1; p.do_gelu = 0; p.addT = nullptr;
        p.outT = nullptr; p.ldo = 0; p.outF = out; p.bsF = 1048576L;
        mfma_gemm<<<dim3(32, 2, 16), 256, 0, stream>>>(p);
    }
}

// Round 12
// 363.986 us; speedup vs baseline: 1.1399x; 1.0990x over previous
//
#include <hip/hip_runtime.h>
#include <math.h>

// ---------------------------------------------------------------------------
// Problem constants: B=16, DIM=256, H=W=64, HEADS=8, C2=16, CF=9, DC=64
// Activations for MFMA are TOKEN-major bf16 [b][4096][C] (K-contiguous).
// f32 kept only for: x (input), qkv (attention), final out.
// ---------------------------------------------------------------------------

typedef __attribute__((ext_vector_type(8))) short bf16x8;
typedef __attribute__((ext_vector_type(4))) float f32x4;

__device__ __forceinline__ float gelu_f(float v) {
    // tanh-GELU in sigmoid form: 0.5v(1+tanh(u)) == v * sigmoid(2u).
    // v_exp + v_rcp only — r11 showed (t-1)/(t+1) emits the slow exact-div
    // sequence (VALUBusy 54%). Limits: v->-inf: exp(+inf)=inf, rcp=0 -> 0 ok;
    // v->+inf: exp(-inf)=0 -> v. Max dev vs exact erf-gelu ~3e-4.
    float u2 = v * (1.5957691216f + 0.0713548162f * v * v);   // 2u
    float t = __expf(-u2);
    return v * __builtin_amdgcn_rcpf(1.0f + t);
}
__device__ __forceinline__ unsigned short f2bf(float f) {
    unsigned u = __builtin_bit_cast(unsigned, f);
    u += 0x7fffu + ((u >> 16) & 1u);
    return (unsigned short)(u >> 16);
}
__device__ __forceinline__ float bf2f(unsigned short h) {
    return __builtin_bit_cast(float, (unsigned)h << 16);
}
__device__ __forceinline__ void store8bf(unsigned short* p, const float* v) {
    unsigned short h[8];
#pragma unroll
    for (int i = 0; i < 8; i++) h[i] = f2bf(v[i]);
    uint4 o;
    o.x = h[0] | ((unsigned)h[1] << 16);
    o.y = h[2] | ((unsigned)h[3] << 16);
    o.z = h[4] | ((unsigned)h[5] << 16);
    o.w = h[6] | ((unsigned)h[7] << 16);
    *(uint4*)p = o;
}

// global -> LDS direct 16B async copy (wave-uniform LDS base, lane scatter i*16)
typedef __attribute__((address_space(1))) void gvoid;
typedef __attribute__((address_space(3))) void svoid;
__device__ __forceinline__ void gl_lds16(const unsigned short* g, unsigned short* l) {
    __builtin_amdgcn_global_load_lds((gvoid*)g, (svoid*)l, 16, 0, 0);
}

// ---------------------------------------------------------------------------
// Merged f32 -> bf16 weight converts (6 segments, one launch)
// ---------------------------------------------------------------------------
__global__ __launch_bounds__(256) void cvt_all(
    const float* __restrict__ a0, unsigned short* __restrict__ d0, int m0,
    const float* __restrict__ a1, unsigned short* __restrict__ d1, int m1,
    const float* __restrict__ a2, unsigned short* __restrict__ d2, int m2,
    const float* __restrict__ a3, unsigned short* __restrict__ d3, int m3,
    const float* __restrict__ a4, unsigned short* __restrict__ d4, int m4,
    const float* __restrict__ a5, unsigned short* __restrict__ d5, int m5)
{
    int sy = blockIdx.y;
    int i = blockIdx.x * 256 + threadIdx.x;
    const float* s; unsigned short* d; int n;
    if      (sy == 0) { s = a0; d = d0; n = m0; }
    else if (sy == 1) { s = a1; d = d1; n = m1; }
    else if (sy == 2) { s = a2; d = d2; n = m2; }
    else if (sy == 3) { s = a3; d = d3; n = m3; }
    else if (sy == 4) { s = a4; d = d4; n = m4; }
    else              { s = a5; d = d5; n = m5; }
    if (i < n) d[i] = f2bf(s[i]);
}

// ---------------------------------------------------------------------------
// Merged conv-weight converts OIHW f32 -> bf16 [tap][oc][ic] (3 segments)
// ---------------------------------------------------------------------------
__global__ __launch_bounds__(256) void cvt_wconv_all(
    const float* __restrict__ w0, unsigned short* __restrict__ o0,
    const float* __restrict__ w1, unsigned short* __restrict__ o1,
    const float* __restrict__ w2, unsigned short* __restrict__ o2)
{
    int sy = blockIdx.y;
    const float* w; unsigned short* wb; int KK;
    if      (sy == 0) { w = w0; wb = o0; KK = 9;  }
    else if (sy == 1) { w = w1; wb = o1; KK = 25; }
    else              { w = w2; wb = o2; KK = 9;  }
    int idx = blockIdx.x * 256 + threadIdx.x;
    if (idx >= 64 * 64 * KK) return;
    int ic = idx & 63, oc = (idx >> 6) & 63, tap = idx >> 12;
    wb[tap * 4096 + oc * 64 + ic] = f2bf(w[(oc * 64 + ic) * KK + tap]);
}

// ---------------------------------------------------------------------------
// x [b][256][4096] f32 -> xT [b][4096][256] bf16 (LDS tile transpose)
// ---------------------------------------------------------------------------
__global__ __launch_bounds__(256) void cvt_xpose(
    const float* __restrict__ x, unsigned short* __restrict__ xT)
{
    __shared__ float tile[64][65];
    const int t = threadIdx.x;
    const int n0 = blockIdx.x * 64, c0 = blockIdx.y * 64, b = blockIdx.z;
    const float* xb = x + (long)b * 1048576;
#pragma unroll
    for (int i = 0; i < 16; i++) {
        int c = i * 4 + (t >> 6), n = t & 63;
        tile[c][n] = xb[(long)(c0 + c) * 4096 + n0 + n];
    }
    __syncthreads();
    unsigned short* xTb = xT + (long)b * 4096 * 256;
#pragma unroll
    for (int i = 0; i < 4; i++) {
        int n = i * 16 + (t >> 4), cc = (t & 15) * 4;
        unsigned short h0 = f2bf(tile[cc + 0][n]);
        unsigned short h1 = f2bf(tile[cc + 1][n]);
        unsigned short h2 = f2bf(tile[cc + 2][n]);
        unsigned short h3 = f2bf(tile[cc + 3][n]);
        uint2 val;
        val.x = h0 | ((unsigned)h1 << 16);
        val.y = h2 | ((unsigned)h3 << 16);
        *(uint2*)&xTb[(long)(n0 + n) * 256 + c0 + cc] = val;
    }
}

// ---------------------------------------------------------------------------
// MFMA bf16 GEMM v6: TRIPLE-buffered gl_lds staging with counted vmcnt and a
// single raw s_barrier per K-step (T3/T4-lite). Replaces the 2-barrier
// __syncthreads loop whose implicit vmcnt(0) drain (~500cy) dominated the
// 16-MFMA step (~80cy): r8/r10/r11 all pinned at ~92us / MfmaUtil 11%.
// Schedule per iter: vmcnt(4|0) [step-k loads landed, k+1 stays in flight]
//   -> s_barrier -> STAGE(k+2 into buf[(k+2)%3]) -> ds_read buf[k%3] + MFMA.
// Race audit: window (bar_k,bar_k+1) writes buf[(k+2)%3] != reads buf[k%3];
// buf[(k+2)%3]'s last readers (iter k-1) are sealed by bar_k. vmcnt counts
// complete in issue order, 4 gl_lds per STAGE per wave.
// ---------------------------------------------------------------------------
#define LDW 32

struct GSel {
    const unsigned short* in1;   // cols [0,c1) source (ld 64), may be null
    const unsigned short* W;     // weights, ld w_ld
    const float* bias;           // may be null
    int c1;
    int col_off;                 // outT column offset
};
struct GemmP {
    GSel sel0, sel1, sel2;
    const unsigned short* in2T;  // cols [c1,K) source (absolute col)
    long ld2;
    int w_ld, rowmap, otiles, K, mode, do_gelu;
    const unsigned short* addT;  // token-major bf16 residual (ld 256), may be null
    unsigned short* outT;        // token-major bf16 out
    int ldo;
    float* outF;                 // channel-major f32 out
    long bsF;
};

__global__ __launch_bounds__(256) void mfma_gemm(GemmP p)
{
    __shared__ unsigned short SM[24576];  // 48KB: A bufs {0,4096,8192}, B bufs {12288+...}
    const int t = threadIdx.x, b = blockIdx.z;
    const int n0 = blockIdx.x * 128;
    const unsigned sy = blockIdx.y;
    const int s  = sy / (unsigned)p.otiles;
    const int ot = sy % (unsigned)p.otiles;
    GSel g = p.sel0;
    if (s == 1) g = p.sel1;
    else if (s == 2) g = p.sel2;
    const int o0 = ot * 128;
    const int w = t >> 6, l = t & 63;
    const int fr = l & 15, fq = l >> 4;
    const int wr = (w >> 1) * 64, wc = (w & 1) * 64;
    const int lrow = l >> 2;
    // source-side segment swizzle (kept from r11 — correctness-neutral)
    const int lcol = (((l & 3) ^ (lrow & 3)) * 8);

    // staging geometry: wave w owns LDS rows [32w,32w+16) and [32w+16,32w+32)
    const int ta0 = 32 * w + lrow, ta1 = ta0 + 16;
    int ra0 = o0 + ta0, ra1 = o0 + ta1;
    if (p.rowmap) {
        ra0 = ((ra0 >> 7) << 8) + (((ra0 >> 4) & 7) << 5) + 16 + (ra0 & 15);
        ra1 = ((ra1 >> 7) << 8) + (((ra1 >> 4) & 7) << 5) + 16 + (ra1 & 15);
    }
    const unsigned short* Ag0 = g.W + (long)ra0 * p.w_ld + lcol;
    const unsigned short* Ag1 = g.W + (long)ra1 * p.w_ld + lcol;
    const unsigned short* i1b = g.in1 ? g.in1 : p.in2T;
    const unsigned short* i1r0 = i1b + ((long)b * 4096 + n0 + ta0) * 64 + lcol;
    const unsigned short* i1r1 = i1r0 + 16L * 64;
    const unsigned short* i2r0 = p.in2T + ((long)b * 4096 + n0 + ta0) * p.ld2 + lcol;
    const unsigned short* i2r1 = i2r0 + 16L * p.ld2;

#define STAGE(BUF, KK) do {                                                    \
        gl_lds16(Ag0 + (KK), &SM[(BUF) * 4096 + (32 * w) * LDW]);              \
        gl_lds16(Ag1 + (KK), &SM[(BUF) * 4096 + (32 * w + 16) * LDW]);         \
        if ((KK) < g.c1) {                                                     \
            gl_lds16(i1r0 + (KK), &SM[12288 + (BUF) * 4096 + (32 * w) * LDW]); \
            gl_lds16(i1r1 + (KK), &SM[12288 + (BUF) * 4096 + (32 * w + 16) * LDW]); \
        } else {                                                               \
            gl_lds16(i2r0 + (KK), &SM[12288 + (BUF) * 4096 + (32 * w) * LDW]); \
            gl_lds16(i2r1 + (KK), &SM[12288 + (BUF) * 4096 + (32 * w + 16) * LDW]); \
        } } while (0)

    f32x4 acc[4][4];
#pragma unroll
    for (int m = 0; m < 4; m++)
#pragma unroll
        for (int n = 0; n < 4; n++) acc[m][n] = (f32x4){0.f, 0.f, 0.f, 0.f};

    // read-side swizzle partner (fr&3 == row&3 for all fragment rows)
    const int sseg = (fq ^ (fr & 3)) * 8;

    const int NK = p.K >> 5;          // always >= 8 here
    STAGE(0, 0);
    STAGE(1, 32);

    for (int ks = 0; ks < NK; ks++) {
        if (ks + 1 < NK) asm volatile("s_waitcnt vmcnt(4)" ::: "memory");
        else             asm volatile("s_waitcnt vmcnt(0)" ::: "memory");
        asm volatile("s_barrier" ::: "memory");
        if (ks + 2 < NK) STAGE((ks + 2) % 3, (ks + 2) << 5);
        const int cur = ks % 3;
        bf16x8 af[4], bv[4];
#pragma unroll
        for (int m = 0; m < 4; m++)
            af[m] = *(const bf16x8*)&SM[cur * 4096 + (wr + m * 16 + fr) * LDW + sseg];
#pragma unroll
        for (int n = 0; n < 4; n++)
            bv[n] = *(const bf16x8*)&SM[12288 + cur * 4096 + (wc + n * 16 + fr) * LDW + sseg];
#pragma unroll
        for (int m = 0; m < 4; m++)
#pragma unroll
            for (int n = 0; n < 4; n++)
                acc[m][n] = __builtin_amdgcn_mfma_f32_16x16x32_bf16(af[m], bv[n], acc[m][n], 0, 0, 0);
    }
#undef STAGE
    __syncthreads();   // seal K-loop (all reads done) before SM reuse in epilogue

    // ---- epilogue ----
    if (p.mode == 0) {
        // LDS-staged coalesced store: two passes of 64 tokens, tile [64][136].
#define EPW 136
#pragma unroll
        for (int pass = 0; pass < 2; pass++) {
            if ((w & 1) == pass) {               // waves whose wc == 64*pass
#pragma unroll
                for (int m = 0; m < 4; m++) {
                    int chm = wr + m * 16 + fq * 4;     // local channel 0..127
                    int ob = o0 + chm;
                    float bm[4] = {0.f, 0.f, 0.f, 0.f};
                    if (g.bias) {
#pragma unroll
                        for (int r = 0; r < 4; r++) bm[r] = g.bias[ob + r];
                    }
#pragma unroll
                    for (int n = 0; n < 4; n++) {
                        int tn = n * 16 + fr;            // local token 0..63
                        int ng = n0 + pass * 64 + tn;
                        float e[4];
#pragma unroll
                        for (int r = 0; r < 4; r++) {
                            e[r] = acc[m][n][r] + bm[r];
                            if (p.do_gelu) e[r] = gelu_f(e[r]);
                        }
                        if (p.addT) {
                            uint2 av = *(const uint2*)&p.addT[((long)b * 4096 + ng) * 256 + ob];
                            e[0] += bf2f((unsigned short)(av.x & 0xffff));
                            e[1] += bf2f((unsigned short)(av.x >> 16));
                            e[2] += bf2f((unsigned short)(av.y & 0xffff));
                            e[3] += bf2f((unsigned short)(av.y >> 16));
                        }
                        unsigned short h[4];
#pragma unroll
                        for (int r = 0; r < 4; r++) h[r] = f2bf(e[r]);
                        uint2 val;
                        val.x = h[0] | ((unsigned)h[1] << 16);
                        val.y = h[2] | ((unsigned)h[3] << 16);
                        *(uint2*)&SM[tn * EPW + chm] = val;
                    }
                }
            }
            __syncthreads();
            // readout: 1024 x 16B chunks; 16 chunks per token row (256 B)
#pragma unroll
            for (int i = 0; i < 4; i++) {
                int c = t + i * 256;
                int tn = c >> 4, pos = c & 15;
                uint4 v = *(const uint4*)&SM[tn * EPW + pos * 8];
                *(uint4*)&p.outT[((long)b * 4096 + n0 + pass * 64 + tn) * (long)p.ldo
                                 + g.col_off + o0 + pos * 8] = v;
            }
            __syncthreads();
        }
#undef EPW
    } else {
        // f32 channel-major epilogue (qkv / proj / out)
#pragma unroll
        for (int m = 0; m < 4; m++) {
            int ob = o0 + wr + m * 16 + fq * 4;
            float bm[4] = {0.f, 0.f, 0.f, 0.f};
            if (g.bias) {
#pragma unroll
                for (int r = 0; r < 4; r++) bm[r] = g.bias[ob + r];
            }
#pragma unroll
            for (int n = 0; n < 4; n++) {
                int ng = n0 + wc + n * 16 + fr;
                float e[4];
#pragma unroll
                for (int r = 0; r < 4; r++) {
                    e[r] = acc[m][n][r] + bm[r];
                    if (p.do_gelu) e[r] = gelu_f(e[r]);
                }
#pragma unroll
                for (int r = 0; r < 4; r++)
                    p.outF[(long)b * p.bsF + (long)(ob + r) * 4096 + ng] = e[r];
            }
        }
    }
}

// ---------------------------------------------------------------------------
// MFMA conv (unchanged — passed).
// ---------------------------------------------------------------------------
template<int K>
__global__ __launch_bounds__(256) void conv_mfma(
    const unsigned short* __restrict__ inT, int ldin,
    const unsigned short* __restrict__ wb,
    unsigned short* __restrict__ outT)
{
    constexpr int R   = K / 2;
    constexpr int NR  = 2 + 2 * R;
    constexpr int W   = 64 + 2 * R;
    constexpr int ICP = 40;
    __shared__ unsigned short lds[NR * W * ICP];
    const int t = threadIdx.x;
    const int b = blockIdx.y;
    const int y0 = blockIdx.x * 2;
    const int w = t >> 6, l = t & 63;
    const int fr = l & 15, fq = l >> 4;
    const int ocw = (w & 1) * 32;
    const int rw  = w >> 1;

    f32x4 acc[2][4];
#pragma unroll
    for (int m = 0; m < 2; m++)
#pragma unroll
        for (int j = 0; j < 4; j++) acc[m][j] = (f32x4){0.f, 0.f, 0.f, 0.f};

    for (int kk = 0; kk < 64; kk += 32) {
        __syncthreads();
        for (int e = t; e < NR * W * 4; e += 256) {
            int part = e & 3;
            int px   = (e >> 2) % W;
            int row  = (e >> 2) / W;
            int gx = px - R, gy = y0 - R + row;
            uint4 v = {0u, 0u, 0u, 0u};
            if ((unsigned)gx < 64u && (unsigned)gy < 64u)
                v = *(const uint4*)&inT[((long)b * 4096 + gy * 64 + gx) * (long)ldin + kk + part * 8];
            *(uint4*)&lds[(row * W + px) * ICP + part * 8] = v;
        }
        __syncthreads();
#pragma unroll
        for (int ky = 0; ky < K; ky++) {
#pragma unroll
            for (int kx = 0; kx < K; kx++) {
                const unsigned short* wt = wb + ((long)((ky * K + kx) * 64 + ocw)) * 64 + kk;
                bf16x8 aw0 = *(const bf16x8*)&wt[fr * 64 + fq * 8];
                bf16x8 aw1 = *(const bf16x8*)&wt[(16 + fr) * 64 + fq * 8];
                const unsigned short* lp = &lds[((rw + ky) * W + kx) * ICP + fq * 8];
#pragma unroll
                for (int j = 0; j < 4; j++) {
                    bf16x8 bt = *(const bf16x8*)&lp[(j * 16 + fr) * ICP];
                    acc[0][j] = __builtin_amdgcn_mfma_f32_16x16x32_bf16(aw0, bt, acc[0][j], 0, 0, 0);
                    acc[1][j] = __builtin_amdgcn_mfma_f32_16x16x32_bf16(aw1, bt, acc[1][j], 0, 0, 0);
                }
            }
        }
    }
    const long tokbase = (long)b * 4096 + (y0 + rw) * 64;
#pragma unroll
    for (int mi = 0; mi < 2; mi++) {
        int oc0 = ocw + mi * 16 + fq * 4;
#pragma unroll
        for (int j = 0; j < 4; j++) {
            long tok = tokbase + j * 16 + fr;
            unsigned short h[4];
#pragma unroll
            for (int r = 0; r < 4; r++) h[r] = f2bf(acc[mi][j][r]);
            uint2 val;
            val.x = h[0] | ((unsigned)h[1] << 16);
            val.y = h[2] | ((unsigned)h[3] << 16);
            *(uint2*)&outT[tok * 64 + oc0] = val;
        }
    }
}

// ---------------------------------------------------------------------------
// Attention (f32, unchanged): reduce -> mats -> apply.
// ---------------------------------------------------------------------------
#define NC 128
#define ST 132

__global__ __launch_bounds__(256) void attn_reduce(
    const float* __restrict__ qkv, float* __restrict__ part)
{
    const int chunk = blockIdx.x, bh = blockIdx.y;
    const int b = bh >> 3, h = bh & 7;
    const int t = threadIdx.x;

    __shared__ float qch[16][ST], kch[16][ST];
    __shared__ float qfr[9][ST], qfi[9][ST], kfr[9][ST], kfi[9][ST];
    __shared__ float ct[9][16], st_[9][16];

    if (t < 144) {
        int f = t / 16, c = t % 16;
        float ang = 6.283185307179586f * (float)(f * c) / 16.0f;
        ct[f][c] = cosf(ang);
        st_[f][c] = sinf(ang);
    }

    const float* qbase = qkv + (long)b * 1572864 + (long)(16 * h) * 4096;
    const float* kbase = qbase + 128 * 4096;

    float s1 = 0.f, sfr = 0.f, sfi = 0.f;
    float qssp = 0.f, kssp = 0.f, qfssp = 0.f, kfssp = 0.f;
    const int c0 = t >> 4, d0 = t & 15;
    const int cf = t / 9, df = t % 9;
    const int rr = t >> 4, jj0 = t & 15;

    const int nlo = chunk * 512, nhi = nlo + 512;
    for (int n0 = nlo; n0 < nhi; n0 += NC) {
        __syncthreads();
#pragma unroll
        for (int i = 0; i < 8; i++) {
            int e = i * 256 + t, row = e >> 7, nn = e & 127;
            qch[row][nn] = qbase[(long)row * 4096 + n0 + nn];
            kch[row][nn] = kbase[(long)row * 4096 + n0 + nn];
        }
        __syncthreads();
        {
            int col = t & 127;
            bool isq = t < 128;
            float vv[16];
#pragma unroll
            for (int c = 0; c < 16; c++) vv[c] = isq ? qch[c][col] : kch[c][col];
#pragma unroll
            for (int f = 0; f < 9; f++) {
                float ar = 0.f, ai = 0.f;
#pragma unroll
                for (int c = 0; c < 16; c++) { ar += vv[c] * ct[f][c]; ai -= vv[c] * st_[f][c]; }
                if (isq) { qfr[f][col] = ar; qfi[f][col] = ai; }
                else     { kfr[f][col] = ar; kfi[f][col] = ai; }
            }
        }
#pragma unroll 4
        for (int n = 0; n < NC; n++) s1 += qch[c0][n] * kch[d0][n];
        for (int n = jj0; n < NC; n += 16) {
            float a = qch[rr][n]; qssp += a * a;
            float bq = kch[rr][n]; kssp += bq * bq;
        }
        __syncthreads();
        if (t < 81) {
#pragma unroll 4
            for (int n = 0; n < NC; n++) {
                float qr = qfr[cf][n], qi = qfi[cf][n];
                float kr = kfr[df][n], ki = kfi[df][n];
                sfr += qr * kr - qi * ki;
                sfi += qr * ki + qi * kr;
            }
        }
        if (t < 144) {
            int f = t >> 4;
            for (int n = jj0; n < NC; n += 16) {
                qfssp += qfr[f][n] * qfr[f][n] + qfi[f][n] * qfi[f][n];
                kfssp += kfr[f][n] * kfr[f][n] + kfi[f][n] * kfi[f][n];
            }
        }
    }

#pragma unroll
    for (int off = 8; off; off >>= 1) {
        qssp  += __shfl_xor(qssp, off);
        kssp  += __shfl_xor(kssp, off);
        qfssp += __shfl_xor(qfssp, off);
        kfssp += __shfl_xor(kfssp, off);
    }
    float* pb = part + (long)(bh * 8 + chunk) * 512;
    pb[t] = s1;
    if (t < 81) { pb[256 + t] = sfr; pb[337 + t] = sfi; }
    if (jj0 == 0) { pb[448 + rr] = qssp; pb[464 + rr] = kssp; }
    if (jj0 == 0 && t < 144) { pb[480 + rr] = qfssp; pb[489 + rr] = kfssp; }
}

__global__ __launch_bounds__(256) void attn_mats(
    const float* __restrict__ part,
    const float* __restrict__ temp1, const float* __restrict__ temp2,
    const float* __restrict__ tw1, const float* __restrict__ tw2,
    float* __restrict__ amats)
{
    const int bh = blockIdx.x;
    const int h = bh & 7;
    const int t = threadIdx.x;

    __shared__ float S1[256], Sfr[81], Sfi[81];
    __shared__ float qss[16], kss[16], qfss[9], kfss[9];

    float s1 = 0.f, sfr = 0.f, sfi = 0.f, a0 = 0.f, a1 = 0.f, a2 = 0.f, a3 = 0.f;
#pragma unroll
    for (int ch = 0; ch < 8; ch++) {
        const float* p = part + (long)(bh * 8 + ch) * 512;
        s1 += p[t];
        if (t < 81) { sfr += p[256 + t]; sfi += p[337 + t]; }
        if (t < 16) { a0 += p[448 + t]; a1 += p[464 + t]; }
        if (t < 9)  { a2 += p[480 + t]; a3 += p[489 + t]; }
    }
    S1[t] = s1;
    if (t < 81) { Sfr[t] = sfr; Sfi[t] = sfi; }
    if (t < 16) { qss[t] = a0; kss[t] = a1; }
    if (t < 9)  { qfss[t] = a2; kfss[t] = a3; }
    __syncthreads();

    const float t1s = temp1[h], t2s = temp2[h];
    float* am = amats + (long)bh * 448;
    if (t < 16) {
        int c = t;
        float nq = fmaxf(sqrtf(qss[c]), 1e-12f);
        float vals[16];
        float m = -1e30f;
#pragma unroll
        for (int d = 0; d < 16; d++) {
            float nk = fmaxf(sqrtf(kss[d]), 1e-12f);
            float v = S1[c * 16 + d] / (nq * nk) * t1s;
            vals[d] = v; m = fmaxf(m, v);
        }
        float s = 0.f;
#pragma unroll
        for (int d = 0; d < 16; d++) { vals[d] = expf(vals[d] - m); s += vals[d]; }
#pragma unroll
        for (int d = 0; d < 16; d++)
            am[c * 16 + d] = vals[d] / s * tw2[(h * 16 + c) * 16 + d];
    }
    if (t >= 32 && t < 41) {
        int c = t - 32;
        float nq = fmaxf(sqrtf(qfss[c]), 1e-12f);
        float vr[9], vi[9];
        float mr = -1e30f, mi = -1e30f;
#pragma unroll
        for (int d = 0; d < 9; d++) {
            float nk = fmaxf(sqrtf(kfss[d]), 1e-12f);
            float sc = t2s / (nq * nk);
            vr[d] = Sfr[c * 9 + d] * sc; vi[d] = Sfi[c * 9 + d] * sc;
            mr = fmaxf(mr, vr[d]); mi = fmaxf(mi, vi[d]);
        }
        float sr = 0.f, si = 0.f;
#pragma unroll
        for (int d = 0; d < 9; d++) {
            vr[d] = expf(vr[d] - mr); sr += vr[d];
            vi[d] = expf(vi[d] - mi); si += vi[d];
        }
#pragma unroll
        for (int d = 0; d < 9; d++) {
            float tw = tw1[(h * 9 + c) * 9 + d];
            am[256 + c * 9 + d] = vr[d] / sr * tw;
            am[337 + c * 9 + d] = vi[d] / si * tw;
        }
    }
}

__global__ __launch_bounds__(256) void attn_apply(
    const float* __restrict__ qkv, const float* __restrict__ amats,
    unsigned short* __restrict__ axT)
{
    const int chunk = blockIdx.x, bh = blockIdx.y;
    const int b = bh >> 3, h = bh & 7;
    const int t = threadIdx.x;

    __shared__ float attn1[16][16], ar2[9][9], ai2[9][9];
    __shared__ float ct[9][16], st_[9][16];

    const float* am = amats + (long)bh * 448;
    attn1[t >> 4][t & 15] = am[t];
    if (t < 81) { ar2[t / 9][t % 9] = am[256 + t]; ai2[t / 9][t % 9] = am[337 + t]; }
    if (t < 144) {
        int f = t / 16, c = t % 16;
        float ang = 6.283185307179586f * (float)(f * c) / 16.0f;
        ct[f][c] = cosf(ang);
        st_[f][c] = sinf(ang);
    }
    __syncthreads();

    const int col = chunk * 256 + t;
    const float* vbase = qkv + (long)b * 1572864 + (long)(256 + 16 * h) * 4096;

    float vv[16];
#pragma unroll
    for (int c = 0; c < 16; c++) vv[c] = vbase[(long)c * 4096 + col];

    float o1[16];
#pragma unroll
    for (int m = 0; m < 16; m++) {
        float a = 0.f;
#pragma unroll
        for (int d = 0; d < 16; d++) a += attn1[m][d] * vv[d];
        o1[m] = a;
    }
    float vfr[9], vfi[9];
#pragma unroll
    for (int f = 0; f < 9; f++) {
        float ar = 0.f, ai = 0.f;
#pragma unroll
        for (int c = 0; c < 16; c++) { ar += vv[c] * ct[f][c]; ai -= vv[c] * st_[f][c]; }
        vfr[f] = ar; vfi[f] = ai;
    }
    float Lr[9], Li[9];
#pragma unroll
    for (int c = 0; c < 9; c++) {
        float lr = 0.f, li = 0.f;
#pragma unroll
        for (int d = 0; d < 9; d++) {
            lr += ar2[c][d] * vfr[d] - ai2[c][d] * vfi[d];
            li += ar2[c][d] * vfi[d] + ai2[c][d] * vfr[d];
        }
        Lr[c] = lr; Li[c] = li;
    }
    float lx[16];
#pragma unroll
    for (int m = 0; m < 16; m++) {
        float s = Lr[0] + ((m & 1) ? -Lr[8] : Lr[8]);
#pragma unroll
        for (int f = 1; f < 8; f++)
            s += 2.0f * (Lr[f] * ct[f][m] - Li[f] * st_[f][m]);
        lx[m] = s * 0.0625f;
    }
    unsigned short* op = axT + ((long)b * 4096 + col) * 256;
    store8bf(op + 16 * h,       lx);
    store8bf(op + 16 * h + 8,   lx + 8);
    store8bf(op + 128 + 16 * h,     o1);
    store8bf(op + 128 + 16 * h + 8, o1 + 8);
}

// ---------------------------------------------------------------------------
// Host launch
// ---------------------------------------------------------------------------
extern "C" void kernel_launch(void* const* d_in, const int* in_sizes, int n_in,
                              void* d_out, int out_size, void* d_ws, size_t ws_size,
                              hipStream_t stream)
{
    const float* x          = (const float*)d_in[0];
    const float* pc3a_w     = (const float*)d_in[1];
    const float* hm_conv1_w = (const float*)d_in[2];
    const float* hm_proj2_w = (const float*)d_in[3];
    const float* hm_proj2_b = (const float*)d_in[4];
    const float* pc5_w      = (const float*)d_in[5];
    const float* hm_conv2_w = (const float*)d_in[6];
    const float* fuse_w     = (const float*)d_in[7];
    const float* qkv_pc3_w  = (const float*)d_in[8];
    const float* qkv_w      = (const float*)d_in[9];
    const float* proj_w     = (const float*)d_in[10];
    const float* proj_b     = (const float*)d_in[11];
    const float* temp1      = (const float*)d_in[12];
    const float* temp2      = (const float*)d_in[13];
    const float* tw1        = (const float*)d_in[14];
    const float* tw2        = (const float*)d_in[15];
    float* out = (float*)d_out;
    char* wsb  = (char*)d_ws;

    // ---- workspace layout (bytes) ----
    unsigned short* catT  = (unsigned short*)(wsb + 0);          // 96 MiB (union qkv f32)
    float*          qkv   = (float*)(wsb + 0);
    unsigned short* xT    = (unsigned short*)(wsb + 100663296);  // 32 MiB (union axT)
    unsigned short* axT   = (unsigned short*)(wsb + 100663296);
    unsigned short* hxT   = (unsigned short*)(wsb + 134217728);  // 32 MiB
    unsigned short* y3T   = (unsigned short*)(wsb + 167772160);  //  8 MiB (reused as yqT)
    unsigned short* yqT   = y3T;
    unsigned short* y5T   = (unsigned short*)(wsb + 176160768);  //  8 MiB (union part/amats)
    float*          part  = (float*)(wsb + 176160768);
    float*          amats = (float*)(wsb + 176160768 + 2097152);
    unsigned short* w1b   = (unsigned short*)(wsb + 184549376);
    unsigned short* w2b   = (unsigned short*)(wsb + 184680448);
    unsigned short* w3b   = (unsigned short*)(wsb + 184811520);
    unsigned short* wfb   = (unsigned short*)(wsb + 184942592);
    unsigned short* wqb   = (unsigned short*)(wsb + 185335808);
    unsigned short* wpb   = (unsigned short*)(wsb + 185729024);
    unsigned short* wc3a  = (unsigned short*)(wsb + 185860096);
    unsigned short* wc5   = (unsigned short*)(wsb + 185933824);
    unsigned short* wc3q  = (unsigned short*)(wsb + 186138624);

    dim3 cvg(32, 16);

    // ---- prep (2 merged convert launches + transpose) ----
    cvt_all<<<dim3(768, 6), 256, 0, stream>>>(
        hm_conv1_w, w1b, 65536,
        hm_proj2_w, w2b, 65536,
        hm_conv2_w, w3b, 65536,
        fuse_w,     wfb, 196608,
        qkv_w,      wqb, 196608,
        proj_w,     wpb, 65536);
    cvt_wconv_all<<<dim3(400, 3), 256, 0, stream>>>(
        pc3a_w, wc3a, pc5_w, wc5, qkv_pc3_w, wc3q);
    cvt_xpose<<<dim3(64, 4, 16), 256, 0, stream>>>(x, xT);

    // ---- both branch convs, then ONE merged branch GEMM (3 sels) ----
    conv_mfma<3><<<cvg, 256, 0, stream>>>(xT, 256, wc3a, y3T);
    conv_mfma<5><<<cvg, 256, 0, stream>>>(xT, 256, wc5, y5T);
    {
        GemmP p = {};
        p.sel0 = { y3T,    w1b, nullptr,     64, 0   };
        p.sel1 = { nullptr, w2b, hm_proj2_b,  0, 256 };
        p.sel2 = { y5T,    w3b, nullptr,     64, 512 };
        p.in2T = xT; p.ld2 = 256;
        p.w_ld = 256; p.rowmap = 0; p.otiles = 2; p.K = 256;
        p.mode = 0; p.do_gelu = 1; p.addT = nullptr;
        p.outT = catT; p.ldo = 768; p.outF = nullptr; p.bsF = 0;
        mfma_gemm<<<dim3(32, 6, 16), 256, 0, stream>>>(p);
    }
    // ---- fuse: hxT = fuse_w @ catT + xT (bf16 residual) ----
    {
        GemmP p = {};
        p.sel0 = { nullptr, wfb, nullptr, 0, 0 };
        p.in2T = catT; p.ld2 = 768;
        p.w_ld = 768; p.rowmap = 0; p.otiles = 2; p.K = 768;
        p.mode = 0; p.do_gelu = 0; p.addT = xT;
        p.outT = hxT; p.ldo = 256; p.outF = nullptr; p.bsF = 0;
        mfma_gemm<<<dim3(32, 2, 16), 256, 0, stream>>>(p);
    }
    // ---- qkv = qkv_w'[384 rows] @ [conv3(hx[:64]); hx[64:]] (f32 ch-major) ----
    conv_mfma<3><<<cvg, 256, 0, stream>>>(hxT, 256, wc3q, yqT);
    {
        GemmP p = {};
        p.sel0 = { yqT, wqb, nullptr, 64, 0 };
        p.in2T = hxT; p.ld2 = 256;
        p.w_ld = 256; p.rowmap = 1; p.otiles = 3; p.K = 256;
        p.mode = 1; p.do_gelu = 0; p.addT = nullptr;
        p.outT = nullptr; p.ldo = 0; p.outF = qkv; p.bsF = 1572864L;
        mfma_gemm<<<dim3(32, 3, 16), 256, 0, stream>>>(p);
    }
    // ---- attention ----
    attn_reduce<<<dim3(8, 128), 256, 0, stream>>>(qkv, part);
    attn_mats<<<128, 256, 0, stream>>>(part, temp1, temp2, tw1, tw2, amats);
    attn_apply<<<dim3(16, 128), 256, 0, stream>>>(qkv, amats, axT);
    // ---- out = proj_w @ axT + proj_b (f32 ch-major) ----
    {
        GemmP p = {};
        p.sel0 = { nullptr, wpb, proj_b, 0, 0 };
        p.in2T = axT; p.ld2 = 256;
        p.w_ld = 256; p.rowmap = 0; p.otiles = 2; p.K = 256;
        p.mode = 1; p.do_gelu = 0; p.addT = nullptr;
        p.outT = nullptr; p.ldo = 0; p.outF = out; p.bsF = 1048576L;
        mfma_gemm<<<dim3(32, 2, 16), 256, 0, stream>>>(p);
    }
}